// Round 16
// baseline (160.068 us; speedup 1.0000x reference)
//
#include <hip/hip_runtime.h>
#include <hip/hip_bf16.h>
#include <math.h>

#define HDIM 1024
#define NHEADS 16
#define HEADD 64
#define SEQLEN 2048
#define NBATCH 2
#define NROWS (NBATCH*SEQLEN)
#define NBH (NBATCH*NHEADS)
#define LOG2E 1.44269504f
#define NT 32   // 64-key tiles per pass

typedef float f32x4 __attribute__((ext_vector_type(4)));
typedef float f32x16 __attribute__((ext_vector_type(16)));
typedef short short8 __attribute__((ext_vector_type(8)));
typedef unsigned short us4v __attribute__((ext_vector_type(4)));

#define GLOBAL_AS __attribute__((address_space(1)))
#define LDS_AS __attribute__((address_space(3)))

union F4 { float4 v; float f[4]; };
union PW { unsigned int u[4]; short8 s; };

static __device__ __forceinline__ unsigned short f2bf(float x) {
    __hip_bfloat16 h = __float2bfloat16(x);
    return *(unsigned short*)&h;
}

// ---------------- LayerNorm -> bf16 ----------------
__global__ __launch_bounds__(256) void ln_kernel(
        const float* __restrict__ x, const float* __restrict__ w,
        const float* __restrict__ b, unsigned short* __restrict__ xn) {
    int row = blockIdx.x;
    F4 vv; vv.v = ((const float4*)(x + (size_t)row*HDIM))[threadIdx.x];
    float s  = vv.f[0]+vv.f[1]+vv.f[2]+vv.f[3];
    float ss = vv.f[0]*vv.f[0]+vv.f[1]*vv.f[1]+vv.f[2]*vv.f[2]+vv.f[3]*vv.f[3];
    #pragma unroll
    for (int off = 32; off > 0; off >>= 1) {
        s  += __shfl_xor(s, off);
        ss += __shfl_xor(ss, off);
    }
    __shared__ float red[8];
    int wid = threadIdx.x >> 6;
    if ((threadIdx.x & 63) == 0) { red[wid] = s; red[wid+4] = ss; }
    __syncthreads();
    s  = red[0]+red[1]+red[2]+red[3];
    ss = red[4]+red[5]+red[6]+red[7];
    float mean = s * (1.0f/HDIM);
    float var  = ss * (1.0f/HDIM) - mean*mean;
    float rstd = rsqrtf(var + 1e-5f);
    F4 wv; wv.v = ((const float4*)w)[threadIdx.x];
    F4 bv; bv.v = ((const float4*)b)[threadIdx.x];
    us4v o;
    #pragma unroll
    for (int j = 0; j < 4; ++j)
        o[j] = f2bf((vv.f[j]-mean)*rstd*wv.f[j] + bv.f[j]);
    *(us4v*)(xn + (size_t)row*HDIM + threadIdx.x*4) = o;
}

// ---------- weight convert+transpose (all 4 in one launch, z=matrix) ----------
__global__ __launch_bounds__(256) void wconv_kernel(
        const float* __restrict__ W0, const float* __restrict__ W1,
        const float* __restrict__ W2, const float* __restrict__ W3,
        unsigned short* __restrict__ WtBase) {
    __shared__ unsigned short T[64*72];
    int z = blockIdx.z;
    const float* W = (z == 0) ? W0 : (z == 1) ? W1 : (z == 2) ? W2 : W3;
    unsigned short* Wt = WtBase + (size_t)z*HDIM*HDIM;
    int k0 = blockIdx.x*64, n0 = blockIdx.y*64;
    int t = threadIdx.x;
    #pragma unroll
    for (int it = 0; it < 4; ++it) {
        int r = (t>>4) + it*16;
        int c = (t&15)*4;
        F4 x; x.v = *(const float4*)(W + (size_t)(k0+r)*HDIM + n0 + c);
        #pragma unroll
        for (int j = 0; j < 4; ++j) T[(c+j)*72 + r] = f2bf(x.f[j]);
    }
    __syncthreads();
    #pragma unroll
    for (int it = 0; it < 2; ++it) {
        int n = (t>>3) + it*32;
        int ch = t&7;
        short8 rowv = *(const short8*)(T + n*72 + ch*8);
        *(short8*)(Wt + (size_t)(n0+n)*HDIM + k0 + ch*8) = rowv;
    }
}

// ------------- fused QKV GEMM: mat = blockIdx.y>>3 (0:Q 1:K 2:V) -------------
__global__ __launch_bounds__(256) void gemm_qkv_kernel(
        const unsigned short* __restrict__ A,
        const unsigned short* __restrict__ WtBase,
        const float* __restrict__ bq, const float* __restrict__ bk,
        const float* __restrict__ bv,
        unsigned short* __restrict__ qb, unsigned short* __restrict__ kb,
        unsigned short* __restrict__ vt) {
    __shared__ unsigned short As[2][128*64];
    __shared__ unsigned short Bs[2][128*64];
    int m0 = blockIdx.x * 128;
    int yy = blockIdx.y;
    int mat = yy >> 3;
    int n0 = (yy & 7) * 128;
    const unsigned short* Wt = WtBase + (size_t)mat*HDIM*HDIM;
    const float* bias = (mat == 0) ? bq : (mat == 1) ? bk : bv;
    int t = threadIdx.x;
    int wid = t >> 6, l = t & 63;
    int wm = wid >> 1, wn = wid & 1;
    int lq = l & 15, g = l >> 4;
    f32x4 acc[4][4];
    #pragma unroll
    for (int mi = 0; mi < 4; ++mi)
        #pragma unroll
        for (int ni = 0; ni < 4; ++ni) acc[mi][ni] = 0.0f;

    auto STAGE = [&](int b, int k0) {
        #pragma unroll
        for (int i = 0; i < 4; ++i) {
            int idx = t + 256*i;
            int r = idx >> 3, ch = idx & 7;
            int gch = ch ^ (r & 7);
            __builtin_amdgcn_global_load_lds(
                (const GLOBAL_AS void*)(A + (size_t)(m0+r)*HDIM + k0 + gch*8),
                (LDS_AS void*)((char*)&As[b][0] + idx*16), 16, 0, 0);
            __builtin_amdgcn_global_load_lds(
                (const GLOBAL_AS void*)(Wt + (size_t)(n0+r)*HDIM + k0 + gch*8),
                (LDS_AS void*)((char*)&Bs[b][0] + idx*16), 16, 0, 0);
        }
    };

    STAGE(0, 0);
    asm volatile("s_waitcnt vmcnt(0)" ::: "memory");
    __builtin_amdgcn_s_barrier();
    asm volatile("" ::: "memory");
    int buf = 0;
    for (int ks = 0; ks < 16; ++ks) {
        if (ks < 15) STAGE(buf^1, (ks+1)*64);
        const char* Ab = (const char*)&As[buf][0];
        const char* Bb = (const char*)&Bs[buf][0];
        #pragma unroll
        for (int kc = 0; kc < 2; ++kc) {
            short8 af[4], bf[4];
            #pragma unroll
            for (int mi = 0; mi < 4; ++mi) {
                int r = wm*64 + mi*16 + lq;
                af[mi] = *(const short8*)(Ab + r*128 + (((kc*4+g) ^ (r&7))<<4));
            }
            #pragma unroll
            for (int ni = 0; ni < 4; ++ni) {
                int r = wn*64 + ni*16 + lq;
                bf[ni] = *(const short8*)(Bb + r*128 + (((kc*4+g) ^ (r&7))<<4));
            }
            #pragma unroll
            for (int mi = 0; mi < 4; ++mi)
                #pragma unroll
                for (int ni = 0; ni < 4; ++ni)
                    acc[mi][ni] = __builtin_amdgcn_mfma_f32_16x16x32_bf16(
                        af[mi], bf[ni], acc[mi][ni], 0, 0, 0);
        }
        asm volatile("s_waitcnt vmcnt(0)" ::: "memory");
        __builtin_amdgcn_s_barrier();
        asm volatile("" ::: "memory");
        buf ^= 1;
    }
    float bvv[4];
    #pragma unroll
    for (int ni = 0; ni < 4; ++ni) bvv[ni] = bias[n0 + wn*64 + ni*16 + lq];
    #pragma unroll
    for (int mi = 0; mi < 4; ++mi)
        #pragma unroll
        for (int ni = 0; ni < 4; ++ni)
            #pragma unroll
            for (int i = 0; i < 4; ++i) acc[mi][ni][i] += bvv[ni];
    int h = (n0 >> 6) + wn;
    if (mat <= 1) {
        unsigned short* outp = (mat == 0) ? qb : kb;
        float oscale = (mat == 0) ? LOG2E : 1.0f;
        #pragma unroll
        for (int mi = 0; mi < 4; ++mi) {
            f32x4 ss = 0.0f;
            #pragma unroll
            for (int ni = 0; ni < 4; ++ni)
                #pragma unroll
                for (int i = 0; i < 4; ++i) ss[i] += acc[mi][ni][i]*acc[mi][ni][i];
            #pragma unroll
            for (int off = 1; off < 16; off <<= 1)
                #pragma unroll
                for (int i = 0; i < 4; ++i) ss[i] += __shfl_xor(ss[i], off);
            #pragma unroll
            for (int i = 0; i < 4; ++i) {
                float sc = oscale / fmaxf(sqrtf(ss[i]), 1e-12f);
                int m = m0 + wm*64 + mi*16 + g*4 + i;
                int bb = m >> 11, sq = m & (SEQLEN-1);
                unsigned short* orow = outp
                    + ((size_t)(bb*NHEADS + h)*SEQLEN + sq)*HEADD;
                #pragma unroll
                for (int ni = 0; ni < 4; ++ni)
                    orow[ni*16 + lq] = f2bf(acc[mi][ni][i] * sc);
            }
        }
    } else {
        #pragma unroll
        for (int mi = 0; mi < 4; ++mi) {
            int m = m0 + wm*64 + mi*16 + g*4;
            int bb = m >> 11, sq = m & (SEQLEN-1);
            #pragma unroll
            for (int ni = 0; ni < 4; ++ni) {
                int d = ni*16 + lq;
                us4v pk;
                #pragma unroll
                for (int i = 0; i < 4; ++i) pk[i] = f2bf(acc[mi][ni][i]);
                *(us4v*)(vt + ((size_t)(bb*NHEADS + h)*HEADD + d)*SEQLEN + sq) = pk;
            }
        }
    }
}

// --------- O-projection GEMM 128x64 tile: out = A@Wt^T + bias + residual ---------
__global__ __launch_bounds__(256) void gemm_o_kernel(
        const unsigned short* __restrict__ A,
        const unsigned short* __restrict__ Wt,
        const float* __restrict__ bias,
        const float* __restrict__ residual,
        float* __restrict__ out) {
    __shared__ unsigned short As[2][128*64];
    __shared__ unsigned short Bs[2][64*64];
    int m0 = blockIdx.x * 128;
    int n0 = blockIdx.y * 64;
    int t = threadIdx.x;
    int wid = t >> 6, l = t & 63;
    int wm = wid >> 1, wn = wid & 1;
    int lq = l & 15, g = l >> 4;
    f32x4 acc[4][2];
    #pragma unroll
    for (int mi = 0; mi < 4; ++mi)
        #pragma unroll
        for (int ni = 0; ni < 2; ++ni) acc[mi][ni] = 0.0f;

    auto STAGE = [&](int b, int k0) {
        #pragma unroll
        for (int i = 0; i < 4; ++i) {
            int idx = t + 256*i;
            int r = idx >> 3, ch = idx & 7;
            int gch = ch ^ (r & 7);
            __builtin_amdgcn_global_load_lds(
                (const GLOBAL_AS void*)(A + (size_t)(m0+r)*HDIM + k0 + gch*8),
                (LDS_AS void*)((char*)&As[b][0] + idx*16), 16, 0, 0);
        }
        #pragma unroll
        for (int i = 0; i < 2; ++i) {
            int idx = t + 256*i;
            int r = idx >> 3, ch = idx & 7;
            int gch = ch ^ (r & 7);
            __builtin_amdgcn_global_load_lds(
                (const GLOBAL_AS void*)(Wt + (size_t)(n0+r)*HDIM + k0 + gch*8),
                (LDS_AS void*)((char*)&Bs[b][0] + idx*16), 16, 0, 0);
        }
    };

    STAGE(0, 0);
    asm volatile("s_waitcnt vmcnt(0)" ::: "memory");
    __builtin_amdgcn_s_barrier();
    asm volatile("" ::: "memory");
    int buf = 0;
    for (int ks = 0; ks < 16; ++ks) {
        if (ks < 15) STAGE(buf^1, (ks+1)*64);
        const char* Ab = (const char*)&As[buf][0];
        const char* Bb = (const char*)&Bs[buf][0];
        #pragma unroll
        for (int kc = 0; kc < 2; ++kc) {
            short8 af[4], bf[2];
            #pragma unroll
            for (int mi = 0; mi < 4; ++mi) {
                int r = wm*64 + mi*16 + lq;
                af[mi] = *(const short8*)(Ab + r*128 + (((kc*4+g) ^ (r&7))<<4));
            }
            #pragma unroll
            for (int ni = 0; ni < 2; ++ni) {
                int r = wn*32 + ni*16 + lq;
                bf[ni] = *(const short8*)(Bb + r*128 + (((kc*4+g) ^ (r&7))<<4));
            }
            #pragma unroll
            for (int mi = 0; mi < 4; ++mi)
                #pragma unroll
                for (int ni = 0; ni < 2; ++ni)
                    acc[mi][ni] = __builtin_amdgcn_mfma_f32_16x16x32_bf16(
                        af[mi], bf[ni], acc[mi][ni], 0, 0, 0);
        }
        asm volatile("s_waitcnt vmcnt(0)" ::: "memory");
        __builtin_amdgcn_s_barrier();
        asm volatile("" ::: "memory");
        buf ^= 1;
    }
    float bvv[2];
    #pragma unroll
    for (int ni = 0; ni < 2; ++ni) bvv[ni] = bias[n0 + wn*32 + ni*16 + lq];
    #pragma unroll
    for (int mi = 0; mi < 4; ++mi)
        #pragma unroll
        for (int i = 0; i < 4; ++i) {
            int m = m0 + wm*64 + mi*16 + g*4 + i;
            float* orow = out + (size_t)m*HDIM;
            const float* rrow = residual + (size_t)m*HDIM;
            #pragma unroll
            for (int ni = 0; ni < 2; ++ni) {
                int n = n0 + wn*32 + ni*16 + lq;
                orow[n] = acc[mi][ni][i] + bvv[ni] + rrow[n];
            }
        }
}

// -- fused 2-step Hopfield attention: 32 q/wave (4 waves/SIMD) + counted vmcnt --
// 512 threads = 4 wq x 2 ks waves; wave: 32 q-rows x one 32-key half.
// 3-tile ring (48 KB -> 2 blocks/CU = 16 waves/CU): stage tile t+2 in phase t,
// vmcnt(2) at phase end. Combines R12's TLP with R15's pipeline — the two
// factors that were each ~null alone (R12 drain-bound, R15 TLP-starved).
// Ring safety: buf written in phase t was last read in phase t-1; the single
// barrier orders read-retire (pre-barrier consumption) before the write issue.
__global__ __launch_bounds__(512, 4) void attn_fused_kernel(
        const unsigned short* __restrict__ qg, const unsigned short* __restrict__ kg,
        const unsigned short* __restrict__ vtg, unsigned short* __restrict__ outp) {
    __shared__ char L[3*16384];   // 48 KiB: ring of 3 {K 8KB | V 8KB} tiles
    int b = blockIdx.x;
    int bh = (b & 7)*4 + ((b >> 3) & 3);   // 4 heads per XCD
    int q0 = (b >> 5) * 128;               // 128 q-rows per block
    int t = threadIdx.x;
    int wid = t >> 6, l = t & 63;
    int wq = wid >> 1, ks = wid & 1;
    int q = l & 31, hi = l >> 5, r7 = q & 7;
    short8 qf[4];
    {
        const unsigned short* qrow = qg + ((size_t)bh*SEQLEN + q0 + wq*32 + q)*HEADD;
        #pragma unroll
        for (int dc = 0; dc < 4; ++dc) qf[dc] = *(const short8*)(qrow + dc*16 + hi*8);
    }
    int koffK0 = q*128 + (((0 + hi) ^ r7) << 4) + ks*4096;
    int koffK1 = q*128 + (((2 + hi) ^ r7) << 4) + ks*4096;
    int koffK2 = q*128 + (((4 + hi) ^ r7) << 4) + ks*4096;
    int koffK3 = q*128 + (((6 + hi) ^ r7) << 4) + ks*4096;
    int vofA = q*128 + (((4*ks + hi) ^ r7) << 4);
    int vofB = q*128 + (((4*ks + 2 + hi) ^ r7) << 4);

    f32x16 o0 = 0.0f, o1 = 0.0f;
    float ls = 0.0f;
    const unsigned short* Kg = kg + (size_t)bh*SEQLEN*HEADD;
    const unsigned short* Vg = vtg + (size_t)bh*HEADD*SEQLEN;
    unsigned int* slot = (unsigned int*)(L + wq*4096);        // overlays buf0
    float* slsum = (float*)(L + 16384 + wq*256);              // overlays buf1

    int sr = t >> 3, sch = t & 7;
    int sgch = sch ^ (sr & 7);
    const unsigned short* Ksrc = Kg + sr*HEADD + sgch*8;
    const unsigned short* Vsrc = Vg + (size_t)sr*SEQLEN + sgch*8;
    auto STAGE = [&](int buf, int kt) {
        __builtin_amdgcn_global_load_lds(
            (const GLOBAL_AS void*)(Ksrc + (size_t)kt*4096),
            (LDS_AS void*)(L + buf*16384 + t*16), 16, 0, 0);
        __builtin_amdgcn_global_load_lds(
            (const GLOBAL_AS void*)(Vsrc + kt*64),
            (LDS_AS void*)(L + buf*16384 + 8192 + t*16), 16, 0, 0);
    };

    auto doTile = [&](const char* T) {
        // ---- S1: K loads + QK ----
        short8 k0 = *(const short8*)(T + koffK0);
        short8 k1 = *(const short8*)(T + koffK1);
        short8 k2 = *(const short8*)(T + koffK2);
        short8 k3 = *(const short8*)(T + koffK3);
        f32x16 s = 0.0f;
        s = __builtin_amdgcn_mfma_f32_32x32x16_bf16(k0, qf[0], s, 0, 0, 0);
        s = __builtin_amdgcn_mfma_f32_32x32x16_bf16(k1, qf[1], s, 0, 0, 0);
        s = __builtin_amdgcn_mfma_f32_32x32x16_bf16(k2, qf[2], s, 0, 0, 0);
        s = __builtin_amdgcn_mfma_f32_32x32x16_bf16(k3, qf[3], s, 0, 0, 0);
        __builtin_amdgcn_sched_barrier(0);
        // ---- S2: V loads + softmax ----
        short8 va0 = *(const short8*)(T + 8192 + vofA);
        short8 va1 = *(const short8*)(T + 8192 + vofA + 4096);
        short8 vb0 = *(const short8*)(T + 8192 + vofB);
        short8 vb1 = *(const short8*)(T + 8192 + vofB + 4096);
        unsigned int w[8];
        float p = 0.0f;
        #pragma unroll
        for (int i = 0; i < 8; ++i) {
            float e0 = __builtin_amdgcn_exp2f(s[2*i]);
            float e1 = __builtin_amdgcn_exp2f(s[2*i+1]);
            p += e0 + e1;
            asm("v_cvt_pk_bf16_f32 %0, %1, %2" : "=v"(w[i]) : "v"(e0), "v"(e1));
        }
        ls += p;
        asm("v_permlane32_swap_b32 %0, %1" : "+v"(w[0]), "+v"(w[2]));
        asm("v_permlane32_swap_b32 %0, %1" : "+v"(w[1]), "+v"(w[3]));
        asm("v_permlane32_swap_b32 %0, %1" : "+v"(w[4]), "+v"(w[6]));
        asm("v_permlane32_swap_b32 %0, %1" : "+v"(w[5]), "+v"(w[7]));
        __builtin_amdgcn_sched_barrier(0);
        // ---- S3: PV ----
        {
            PW pa, pb;
            pa.u[0]=w[0]; pa.u[1]=w[1]; pa.u[2]=w[2]; pa.u[3]=w[3];
            pb.u[0]=w[4]; pb.u[1]=w[5]; pb.u[2]=w[6]; pb.u[3]=w[7];
            __builtin_amdgcn_s_setprio(1);
            o0 = __builtin_amdgcn_mfma_f32_32x32x16_bf16(va0, pa.s, o0, 0, 0, 0);
            o1 = __builtin_amdgcn_mfma_f32_32x32x16_bf16(va1, pa.s, o1, 0, 0, 0);
            o0 = __builtin_amdgcn_mfma_f32_32x32x16_bf16(vb0, pb.s, o0, 0, 0, 0);
            o1 = __builtin_amdgcn_mfma_f32_32x32x16_bf16(vb1, pb.s, o1, 0, 0, 0);
            __builtin_amdgcn_s_setprio(0);
        }
    };

    auto runPass = [&]() {
        int cur = 0;
        #pragma unroll 1
        for (int kt = 0; kt < NT; ++kt) {
            bool pre = (kt + 2 < NT);
            if (pre) {
                int nb = cur + 2; if (nb >= 3) nb -= 3;
                STAGE(nb, kt + 2);
            }
            doTile(L + cur*16384);
            if (pre) asm volatile("s_waitcnt vmcnt(2)" ::: "memory");
            else     asm volatile("s_waitcnt vmcnt(0)" ::: "memory");
            __builtin_amdgcn_s_barrier();
            asm volatile("" ::: "memory");
            cur = (cur == 2) ? 0 : cur + 1;
        }
    };

    auto prologue = [&]() {
        STAGE(0, 0); STAGE(1, 1);
        asm volatile("s_waitcnt vmcnt(2)" ::: "memory");   // tile0 landed
        __builtin_amdgcn_s_barrier();
        asm volatile("" ::: "memory");
    };

    // ---- pass 1 ----
    prologue();
    runPass();
    ls += __shfl_xor(ls, 32);   // combine hi-halves (each lane held 16 of 32 keys)
    // ---- pass boundary: combine ks halves, compute state1, share qf ----
    if (ks == 1) {
        #pragma unroll
        for (int i = 0; i < 8; ++i) {
            unsigned int u;
            asm("v_cvt_pk_bf16_f32 %0, %1, %2" : "=v"(u) : "v"(o0[2*i]), "v"(o0[2*i+1]));
            slot[i*64 + l] = u;
            asm("v_cvt_pk_bf16_f32 %0, %1, %2" : "=v"(u) : "v"(o1[2*i]), "v"(o1[2*i+1]));
            slot[(8+i)*64 + l] = u;
        }
        slsum[l] = ls;
        asm volatile("s_waitcnt lgkmcnt(0)" ::: "memory");
    }
    __builtin_amdgcn_s_barrier();
    asm volatile("" ::: "memory");
    if (ks == 0) {
        #pragma unroll
        for (int i = 0; i < 8; ++i) {
            unsigned int u = slot[i*64 + l];
            o0[2*i]   += __uint_as_float(u << 16);
            o0[2*i+1] += __uint_as_float(u & 0xffff0000u);
            u = slot[(8+i)*64 + l];
            o1[2*i]   += __uint_as_float(u << 16);
            o1[2*i+1] += __uint_as_float(u & 0xffff0000u);
        }
        float osc = LOG2E / (ls + slsum[l]);
        unsigned int w0[8], w1[8];
        #pragma unroll
        for (int i = 0; i < 8; ++i) {
            float a0 = o0[2*i]*osc, a1 = o0[2*i+1]*osc;
            asm("v_cvt_pk_bf16_f32 %0, %1, %2" : "=v"(w0[i]) : "v"(a0), "v"(a1));
            float b0 = o1[2*i]*osc, b1 = o1[2*i+1]*osc;
            asm("v_cvt_pk_bf16_f32 %0, %1, %2" : "=v"(w1[i]) : "v"(b0), "v"(b1));
        }
        asm volatile("v_permlane32_swap_b32 %0, %1" : "+v"(w0[0]), "+v"(w0[2]));
        asm volatile("v_permlane32_swap_b32 %0, %1" : "+v"(w0[1]), "+v"(w0[3]));
        asm volatile("v_permlane32_swap_b32 %0, %1" : "+v"(w0[4]), "+v"(w0[6]));
        asm volatile("v_permlane32_swap_b32 %0, %1" : "+v"(w0[5]), "+v"(w0[7]));
        asm volatile("v_permlane32_swap_b32 %0, %1" : "+v"(w1[0]), "+v"(w1[2]));
        asm volatile("v_permlane32_swap_b32 %0, %1" : "+v"(w1[1]), "+v"(w1[3]));
        asm volatile("v_permlane32_swap_b32 %0, %1" : "+v"(w1[4]), "+v"(w1[6]));
        asm volatile("v_permlane32_swap_b32 %0, %1" : "+v"(w1[5]), "+v"(w1[7]));
        PW pa;
        pa.u[0]=w0[0]; pa.u[1]=w0[1]; pa.u[2]=w0[2]; pa.u[3]=w0[3]; qf[0]=pa.s;
        pa.u[0]=w0[4]; pa.u[1]=w0[5]; pa.u[2]=w0[6]; pa.u[3]=w0[7]; qf[1]=pa.s;
        pa.u[0]=w1[0]; pa.u[1]=w1[1]; pa.u[2]=w1[2]; pa.u[3]=w1[3]; qf[2]=pa.s;
        pa.u[0]=w1[4]; pa.u[1]=w1[5]; pa.u[2]=w1[6]; pa.u[3]=w1[7]; qf[3]=pa.s;
        #pragma unroll
        for (int i = 0; i < 8; ++i) {
            slot[i*64 + l] = w0[i];
            slot[(8+i)*64 + l] = w1[i];
        }
        asm volatile("s_waitcnt lgkmcnt(0)" ::: "memory");
    }
    __builtin_amdgcn_s_barrier();
    asm volatile("" ::: "memory");
    if (ks == 1) {
        PW pa;
        pa.u[0]=slot[0*64+l]; pa.u[1]=slot[1*64+l]; pa.u[2]=slot[2*64+l]; pa.u[3]=slot[3*64+l]; qf[0]=pa.s;
        pa.u[0]=slot[4*64+l]; pa.u[1]=slot[5*64+l]; pa.u[2]=slot[6*64+l]; pa.u[3]=slot[7*64+l]; qf[1]=pa.s;
        pa.u[0]=slot[8*64+l]; pa.u[1]=slot[9*64+l]; pa.u[2]=slot[10*64+l]; pa.u[3]=slot[11*64+l]; qf[2]=pa.s;
        pa.u[0]=slot[12*64+l]; pa.u[1]=slot[13*64+l]; pa.u[2]=slot[14*64+l]; pa.u[3]=slot[15*64+l]; qf[3]=pa.s;
    }
    asm volatile("s_waitcnt lgkmcnt(0)" ::: "memory");
    __builtin_amdgcn_s_barrier();
    asm volatile("" ::: "memory");
    o0 = 0.0f; o1 = 0.0f; ls = 0.0f;
    // ---- pass 2 ----
    prologue();
    runPass();
    ls += __shfl_xor(ls, 32);
    // ---- final combine + output ----
    if (ks == 1) {
        #pragma unroll
        for (int i = 0; i < 8; ++i) {
            unsigned int u;
            asm("v_cvt_pk_bf16_f32 %0, %1, %2" : "=v"(u) : "v"(o0[2*i]), "v"(o0[2*i+1]));
            slot[i*64 + l] = u;
            asm("v_cvt_pk_bf16_f32 %0, %1, %2" : "=v"(u) : "v"(o1[2*i]), "v"(o1[2*i+1]));
            slot[(8+i)*64 + l] = u;
        }
        slsum[l] = ls;
        asm volatile("s_waitcnt lgkmcnt(0)" ::: "memory");
    }
    __builtin_amdgcn_s_barrier();
    asm volatile("" ::: "memory");
    if (ks == 0) {
        #pragma unroll
        for (int i = 0; i < 8; ++i) {
            unsigned int u = slot[i*64 + l];
            o0[2*i]   += __uint_as_float(u << 16);
            o0[2*i+1] += __uint_as_float(u & 0xffff0000u);
            u = slot[(8+i)*64 + l];
            o1[2*i]   += __uint_as_float(u << 16);
            o1[2*i+1] += __uint_as_float(u & 0xffff0000u);
        }
        float osc = 1.0f / (ls + slsum[l]);
        int bb = bh >> 4, hh = bh & 15;
        unsigned short* orow = outp + ((size_t)bb*SEQLEN + q0 + wq*32 + q)*HDIM + hh*HEADD;
        const int dtab[8] = {0,2,8,10,16,18,24,26};
        #pragma unroll
        for (int i = 0; i < 8; ++i) {
            int d = dtab[i] + 4*hi;
            unsigned int wv;
            float a0 = o0[2*i]*osc, a1 = o0[2*i+1]*osc;
            asm("v_cvt_pk_bf16_f32 %0, %1, %2" : "=v"(wv) : "v"(a0), "v"(a1));
            *(unsigned int*)(orow + d) = wv;
            float c0 = o1[2*i]*osc, c1 = o1[2*i+1]*osc;
            asm("v_cvt_pk_bf16_f32 %0, %1, %2" : "=v"(wv) : "v"(c0), "v"(c1));
            *(unsigned int*)(orow + 32 + d) = wv;
        }
    }
}

extern "C" void kernel_launch(void* const* d_in, const int* in_sizes, int n_in,
                              void* d_out, int out_size, void* d_ws, size_t ws_size,
                              hipStream_t stream) {
    const float* hs = (const float*)d_in[0];
    const float* Wq = (const float*)d_in[1];
    const float* bq = (const float*)d_in[2];
    const float* Wk = (const float*)d_in[3];
    const float* bk = (const float*)d_in[4];
    const float* Wv = (const float*)d_in[5];
    const float* bv = (const float*)d_in[6];
    const float* Wo = (const float*)d_in[7];
    const float* bo = (const float*)d_in[8];
    const float* lw = (const float*)d_in[9];
    const float* lb = (const float*)d_in[10];
    unsigned short* ws16 = (unsigned short*)d_ws;
    const size_t NE = (size_t)NROWS * HDIM;
    const size_t WE = (size_t)HDIM * HDIM;
    unsigned short* xn  = ws16;
    unsigned short* Wtq = xn + NE;       // Wtq/Wtk/Wtv/Wto contiguous
    unsigned short* Wto = Wtq + 3*WE;
    unsigned short* qb  = Wtq + 4*WE;
    unsigned short* kb  = qb + NE;
    unsigned short* vt  = kb + NE;
    unsigned short* s2  = vt + NE;

    ln_kernel<<<NROWS, 256, 0, stream>>>(hs, lw, lb, xn);
    wconv_kernel<<<dim3(HDIM/64, HDIM/64, 4), 256, 0, stream>>>(Wq, Wk, Wv, Wo, Wtq);
    gemm_qkv_kernel<<<dim3(NROWS/128, 24), 256, 0, stream>>>(xn, Wtq, bq, bk, bv, qb, kb, vt);
    attn_fused_kernel<<<NBH*16, 512, 0, stream>>>(qb, kb, vt, s2);
    gemm_o_kernel<<<dim3(NROWS/128, HDIM/64), 256, 0, stream>>>(s2, Wto, bo, hs, (float*)d_out);
}

// Round 17
// 155.571 us; speedup vs baseline: 1.0289x; 1.0289x over previous
//
#include <hip/hip_runtime.h>
#include <hip/hip_bf16.h>
#include <math.h>

#define HDIM 1024
#define NHEADS 16
#define HEADD 64
#define SEQLEN 2048
#define NBATCH 2
#define NROWS (NBATCH*SEQLEN)
#define NBH (NBATCH*NHEADS)
#define LOG2E 1.44269504f
#define NT 32   // 64-key tiles per pass

typedef float f32x4 __attribute__((ext_vector_type(4)));
typedef float f32x16 __attribute__((ext_vector_type(16)));
typedef short short8 __attribute__((ext_vector_type(8)));
typedef unsigned short us4v __attribute__((ext_vector_type(4)));

#define GLOBAL_AS __attribute__((address_space(1)))
#define LDS_AS __attribute__((address_space(3)))

union F4 { float4 v; float f[4]; };
union PW { unsigned int u[4]; short8 s; };

static __device__ __forceinline__ unsigned short f2bf(float x) {
    __hip_bfloat16 h = __float2bfloat16(x);
    return *(unsigned short*)&h;
}

// ---------------- LayerNorm -> bf16 ----------------
__global__ __launch_bounds__(256) void ln_kernel(
        const float* __restrict__ x, const float* __restrict__ w,
        const float* __restrict__ b, unsigned short* __restrict__ xn) {
    int row = blockIdx.x;
    F4 vv; vv.v = ((const float4*)(x + (size_t)row*HDIM))[threadIdx.x];
    float s  = vv.f[0]+vv.f[1]+vv.f[2]+vv.f[3];
    float ss = vv.f[0]*vv.f[0]+vv.f[1]*vv.f[1]+vv.f[2]*vv.f[2]+vv.f[3]*vv.f[3];
    #pragma unroll
    for (int off = 32; off > 0; off >>= 1) {
        s  += __shfl_xor(s, off);
        ss += __shfl_xor(ss, off);
    }
    __shared__ float red[8];
    int wid = threadIdx.x >> 6;
    if ((threadIdx.x & 63) == 0) { red[wid] = s; red[wid+4] = ss; }
    __syncthreads();
    s  = red[0]+red[1]+red[2]+red[3];
    ss = red[4]+red[5]+red[6]+red[7];
    float mean = s * (1.0f/HDIM);
    float var  = ss * (1.0f/HDIM) - mean*mean;
    float rstd = rsqrtf(var + 1e-5f);
    F4 wv; wv.v = ((const float4*)w)[threadIdx.x];
    F4 bv; bv.v = ((const float4*)b)[threadIdx.x];
    us4v o;
    #pragma unroll
    for (int j = 0; j < 4; ++j)
        o[j] = f2bf((vv.f[j]-mean)*rstd*wv.f[j] + bv.f[j]);
    *(us4v*)(xn + (size_t)row*HDIM + threadIdx.x*4) = o;
}

// ---------- weight convert+transpose (all 4 in one launch, z=matrix) ----------
__global__ __launch_bounds__(256) void wconv_kernel(
        const float* __restrict__ W0, const float* __restrict__ W1,
        const float* __restrict__ W2, const float* __restrict__ W3,
        unsigned short* __restrict__ WtBase) {
    __shared__ unsigned short T[64*72];
    int z = blockIdx.z;
    const float* W = (z == 0) ? W0 : (z == 1) ? W1 : (z == 2) ? W2 : W3;
    unsigned short* Wt = WtBase + (size_t)z*HDIM*HDIM;
    int k0 = blockIdx.x*64, n0 = blockIdx.y*64;
    int t = threadIdx.x;
    #pragma unroll
    for (int it = 0; it < 4; ++it) {
        int r = (t>>4) + it*16;
        int c = (t&15)*4;
        F4 x; x.v = *(const float4*)(W + (size_t)(k0+r)*HDIM + n0 + c);
        #pragma unroll
        for (int j = 0; j < 4; ++j) T[(c+j)*72 + r] = f2bf(x.f[j]);
    }
    __syncthreads();
    #pragma unroll
    for (int it = 0; it < 2; ++it) {
        int n = (t>>3) + it*32;
        int ch = t&7;
        short8 rowv = *(const short8*)(T + n*72 + ch*8);
        *(short8*)(Wt + (size_t)(n0+n)*HDIM + k0 + ch*8) = rowv;
    }
}

// ------------- fused QKV GEMM: mat = blockIdx.y>>3 (0:Q 1:K 2:V) -------------
__global__ __launch_bounds__(256) void gemm_qkv_kernel(
        const unsigned short* __restrict__ A,
        const unsigned short* __restrict__ WtBase,
        const float* __restrict__ bq, const float* __restrict__ bk,
        const float* __restrict__ bv,
        unsigned short* __restrict__ qb, unsigned short* __restrict__ kb,
        unsigned short* __restrict__ vt) {
    __shared__ unsigned short As[2][128*64];
    __shared__ unsigned short Bs[2][128*64];
    int m0 = blockIdx.x * 128;
    int yy = blockIdx.y;
    int mat = yy >> 3;
    int n0 = (yy & 7) * 128;
    const unsigned short* Wt = WtBase + (size_t)mat*HDIM*HDIM;
    const float* bias = (mat == 0) ? bq : (mat == 1) ? bk : bv;
    int t = threadIdx.x;
    int wid = t >> 6, l = t & 63;
    int wm = wid >> 1, wn = wid & 1;
    int lq = l & 15, g = l >> 4;
    f32x4 acc[4][4];
    #pragma unroll
    for (int mi = 0; mi < 4; ++mi)
        #pragma unroll
        for (int ni = 0; ni < 4; ++ni) acc[mi][ni] = 0.0f;

    auto STAGE = [&](int b, int k0) {
        #pragma unroll
        for (int i = 0; i < 4; ++i) {
            int idx = t + 256*i;
            int r = idx >> 3, ch = idx & 7;
            int gch = ch ^ (r & 7);
            __builtin_amdgcn_global_load_lds(
                (const GLOBAL_AS void*)(A + (size_t)(m0+r)*HDIM + k0 + gch*8),
                (LDS_AS void*)((char*)&As[b][0] + idx*16), 16, 0, 0);
            __builtin_amdgcn_global_load_lds(
                (const GLOBAL_AS void*)(Wt + (size_t)(n0+r)*HDIM + k0 + gch*8),
                (LDS_AS void*)((char*)&Bs[b][0] + idx*16), 16, 0, 0);
        }
    };

    STAGE(0, 0);
    asm volatile("s_waitcnt vmcnt(0)" ::: "memory");
    __builtin_amdgcn_s_barrier();
    asm volatile("" ::: "memory");
    int buf = 0;
    for (int ks = 0; ks < 16; ++ks) {
        if (ks < 15) STAGE(buf^1, (ks+1)*64);
        const char* Ab = (const char*)&As[buf][0];
        const char* Bb = (const char*)&Bs[buf][0];
        #pragma unroll
        for (int kc = 0; kc < 2; ++kc) {
            short8 af[4], bf[4];
            #pragma unroll
            for (int mi = 0; mi < 4; ++mi) {
                int r = wm*64 + mi*16 + lq;
                af[mi] = *(const short8*)(Ab + r*128 + (((kc*4+g) ^ (r&7))<<4));
            }
            #pragma unroll
            for (int ni = 0; ni < 4; ++ni) {
                int r = wn*64 + ni*16 + lq;
                bf[ni] = *(const short8*)(Bb + r*128 + (((kc*4+g) ^ (r&7))<<4));
            }
            #pragma unroll
            for (int mi = 0; mi < 4; ++mi)
                #pragma unroll
                for (int ni = 0; ni < 4; ++ni)
                    acc[mi][ni] = __builtin_amdgcn_mfma_f32_16x16x32_bf16(
                        af[mi], bf[ni], acc[mi][ni], 0, 0, 0);
        }
        asm volatile("s_waitcnt vmcnt(0)" ::: "memory");
        __builtin_amdgcn_s_barrier();
        asm volatile("" ::: "memory");
        buf ^= 1;
    }
    float bvv[4];
    #pragma unroll
    for (int ni = 0; ni < 4; ++ni) bvv[ni] = bias[n0 + wn*64 + ni*16 + lq];
    #pragma unroll
    for (int mi = 0; mi < 4; ++mi)
        #pragma unroll
        for (int ni = 0; ni < 4; ++ni)
            #pragma unroll
            for (int i = 0; i < 4; ++i) acc[mi][ni][i] += bvv[ni];
    int h = (n0 >> 6) + wn;
    if (mat <= 1) {
        unsigned short* outp = (mat == 0) ? qb : kb;
        float oscale = (mat == 0) ? LOG2E : 1.0f;
        #pragma unroll
        for (int mi = 0; mi < 4; ++mi) {
            f32x4 ss = 0.0f;
            #pragma unroll
            for (int ni = 0; ni < 4; ++ni)
                #pragma unroll
                for (int i = 0; i < 4; ++i) ss[i] += acc[mi][ni][i]*acc[mi][ni][i];
            #pragma unroll
            for (int off = 1; off < 16; off <<= 1)
                #pragma unroll
                for (int i = 0; i < 4; ++i) ss[i] += __shfl_xor(ss[i], off);
            #pragma unroll
            for (int i = 0; i < 4; ++i) {
                float sc = oscale / fmaxf(sqrtf(ss[i]), 1e-12f);
                int m = m0 + wm*64 + mi*16 + g*4 + i;
                int bb = m >> 11, sq = m & (SEQLEN-1);
                unsigned short* orow = outp
                    + ((size_t)(bb*NHEADS + h)*SEQLEN + sq)*HEADD;
                #pragma unroll
                for (int ni = 0; ni < 4; ++ni)
                    orow[ni*16 + lq] = f2bf(acc[mi][ni][i] * sc);
            }
        }
    } else {
        #pragma unroll
        for (int mi = 0; mi < 4; ++mi) {
            int m = m0 + wm*64 + mi*16 + g*4;
            int bb = m >> 11, sq = m & (SEQLEN-1);
            #pragma unroll
            for (int ni = 0; ni < 4; ++ni) {
                int d = ni*16 + lq;
                us4v pk;
                #pragma unroll
                for (int i = 0; i < 4; ++i) pk[i] = f2bf(acc[mi][ni][i]);
                *(us4v*)(vt + ((size_t)(bb*NHEADS + h)*HEADD + d)*SEQLEN + sq) = pk;
            }
        }
    }
}

// --------- O-projection GEMM 128x64 tile: out = A@Wt^T + bias + residual ---------
__global__ __launch_bounds__(256) void gemm_o_kernel(
        const unsigned short* __restrict__ A,
        const unsigned short* __restrict__ Wt,
        const float* __restrict__ bias,
        const float* __restrict__ residual,
        float* __restrict__ out) {
    __shared__ unsigned short As[2][128*64];
    __shared__ unsigned short Bs[2][64*64];
    int m0 = blockIdx.x * 128;
    int n0 = blockIdx.y * 64;
    int t = threadIdx.x;
    int wid = t >> 6, l = t & 63;
    int wm = wid >> 1, wn = wid & 1;
    int lq = l & 15, g = l >> 4;
    f32x4 acc[4][2];
    #pragma unroll
    for (int mi = 0; mi < 4; ++mi)
        #pragma unroll
        for (int ni = 0; ni < 2; ++ni) acc[mi][ni] = 0.0f;

    auto STAGE = [&](int b, int k0) {
        #pragma unroll
        for (int i = 0; i < 4; ++i) {
            int idx = t + 256*i;
            int r = idx >> 3, ch = idx & 7;
            int gch = ch ^ (r & 7);
            __builtin_amdgcn_global_load_lds(
                (const GLOBAL_AS void*)(A + (size_t)(m0+r)*HDIM + k0 + gch*8),
                (LDS_AS void*)((char*)&As[b][0] + idx*16), 16, 0, 0);
        }
        #pragma unroll
        for (int i = 0; i < 2; ++i) {
            int idx = t + 256*i;
            int r = idx >> 3, ch = idx & 7;
            int gch = ch ^ (r & 7);
            __builtin_amdgcn_global_load_lds(
                (const GLOBAL_AS void*)(Wt + (size_t)(n0+r)*HDIM + k0 + gch*8),
                (LDS_AS void*)((char*)&Bs[b][0] + idx*16), 16, 0, 0);
        }
    };

    STAGE(0, 0);
    asm volatile("s_waitcnt vmcnt(0)" ::: "memory");
    __builtin_amdgcn_s_barrier();
    asm volatile("" ::: "memory");
    int buf = 0;
    for (int ks = 0; ks < 16; ++ks) {
        if (ks < 15) STAGE(buf^1, (ks+1)*64);
        const char* Ab = (const char*)&As[buf][0];
        const char* Bb = (const char*)&Bs[buf][0];
        #pragma unroll
        for (int kc = 0; kc < 2; ++kc) {
            short8 af[4], bf[2];
            #pragma unroll
            for (int mi = 0; mi < 4; ++mi) {
                int r = wm*64 + mi*16 + lq;
                af[mi] = *(const short8*)(Ab + r*128 + (((kc*4+g) ^ (r&7))<<4));
            }
            #pragma unroll
            for (int ni = 0; ni < 2; ++ni) {
                int r = wn*32 + ni*16 + lq;
                bf[ni] = *(const short8*)(Bb + r*128 + (((kc*4+g) ^ (r&7))<<4));
            }
            #pragma unroll
            for (int mi = 0; mi < 4; ++mi)
                #pragma unroll
                for (int ni = 0; ni < 2; ++ni)
                    acc[mi][ni] = __builtin_amdgcn_mfma_f32_16x16x32_bf16(
                        af[mi], bf[ni], acc[mi][ni], 0, 0, 0);
        }
        asm volatile("s_waitcnt vmcnt(0)" ::: "memory");
        __builtin_amdgcn_s_barrier();
        asm volatile("" ::: "memory");
        buf ^= 1;
    }
    float bvv[2];
    #pragma unroll
    for (int ni = 0; ni < 2; ++ni) bvv[ni] = bias[n0 + wn*32 + ni*16 + lq];
    #pragma unroll
    for (int mi = 0; mi < 4; ++mi)
        #pragma unroll
        for (int i = 0; i < 4; ++i) {
            int m = m0 + wm*64 + mi*16 + g*4 + i;
            float* orow = out + (size_t)m*HDIM;
            const float* rrow = residual + (size_t)m*HDIM;
            #pragma unroll
            for (int ni = 0; ni < 2; ++ni) {
                int n = n0 + wn*32 + ni*16 + lq;
                orow[n] = acc[mi][ni][i] + bvv[ni] + rrow[n];
            }
        }
}

// ------- fused 2-step Hopfield attention (R15 base + VALU->MFMA shifts) -------
// 512 threads = 4 wq x 2 ks waves; wave: 64 q (streams A,B) x 32 keys.
// 8 staging buffers, counted vmcnt(4) (R15's proven pipeline).
// NEW: lsum via ones-MFMA (kills the 64-add serial chain + shfl per tile);
//      sA/sB start from hoisted FZERO via MFMA C-operand (kills 32 movs/tile).
__global__ __launch_bounds__(512, 2) void attn_fused_kernel(
        const unsigned short* __restrict__ qg, const unsigned short* __restrict__ kg,
        const unsigned short* __restrict__ vtg, unsigned short* __restrict__ outp) {
    __shared__ char L[8*16384];   // 128 KiB: ring of 4 tile-pairs
    int b = blockIdx.x;
    int bh = (b & 7)*4 + ((b >> 3) & 3);   // 4 heads per XCD
    int q0 = (b >> 5) * 256;               // 256 q-rows per block
    int t = threadIdx.x;
    int wid = t >> 6, l = t & 63;
    int wq = wid >> 1, ks = wid & 1;
    int q = l & 31, hi = l >> 5, r7 = q & 7;
    short8 qfA[4], qfB[4];
    {
        const unsigned short* qrowA = qg + ((size_t)bh*SEQLEN + q0 + wq*64 + q)*HEADD;
        const unsigned short* qrowB = qrowA + 32*HEADD;
        #pragma unroll
        for (int dc = 0; dc < 4; ++dc) {
            qfA[dc] = *(const short8*)(qrowA + dc*16 + hi*8);
            qfB[dc] = *(const short8*)(qrowB + dc*16 + hi*8);
        }
    }
    int koffK0 = q*128 + (((0 + hi) ^ r7) << 4) + ks*4096;
    int koffK1 = q*128 + (((2 + hi) ^ r7) << 4) + ks*4096;
    int koffK2 = q*128 + (((4 + hi) ^ r7) << 4) + ks*4096;
    int koffK3 = q*128 + (((6 + hi) ^ r7) << 4) + ks*4096;
    int vofA = q*128 + (((4*ks + hi) ^ r7) << 4);
    int vofB = q*128 + (((4*ks + 2 + hi) ^ r7) << 4);
    short8 ones;
    #pragma unroll
    for (int j = 0; j < 8; ++j) ones[j] = (short)0x3F80;   // bf16 1.0
    const f32x16 FZERO = 0.0f;

    f32x16 oA0 = 0.0f, oA1 = 0.0f, oB0 = 0.0f, oB1 = 0.0f;
    f32x16 oLA = 0.0f, oLB = 0.0f;   // lsum accumulators (all regs identical)
    const unsigned short* Kg = kg + (size_t)bh*SEQLEN*HEADD;
    const unsigned short* Vg = vtg + (size_t)bh*HEADD*SEQLEN;
    unsigned int* slotA = (unsigned int*)(L + wq*4096);            // buf0
    unsigned int* slotB = (unsigned int*)(L + 16384 + wq*4096);    // buf1
    float* slsA = (float*)(L + 32768 + wq*512);                    // buf2 front
    float* slsB = slsA + 64;

    int sr = t >> 3, sch = t & 7;
    int sgch = sch ^ (sr & 7);
    const unsigned short* Ksrc = Kg + sr*HEADD + sgch*8;
    const unsigned short* Vsrc = Vg + (size_t)sr*SEQLEN + sgch*8;
    auto STAGE = [&](int buf, int kt) {
        __builtin_amdgcn_global_load_lds(
            (const GLOBAL_AS void*)(Ksrc + (size_t)kt*4096),
            (LDS_AS void*)(L + buf*16384 + t*16), 16, 0, 0);
        __builtin_amdgcn_global_load_lds(
            (const GLOBAL_AS void*)(Vsrc + kt*64),
            (LDS_AS void*)(L + buf*16384 + 8192 + t*16), 16, 0, 0);
    };

    auto doTile = [&](const char* T) {
        // ---- S1: K loads + QK of BOTH streams (C-in = FZERO, no movs) ----
        short8 k0 = *(const short8*)(T + koffK0);
        short8 k1 = *(const short8*)(T + koffK1);
        short8 k2 = *(const short8*)(T + koffK2);
        short8 k3 = *(const short8*)(T + koffK3);
        f32x16 sA = __builtin_amdgcn_mfma_f32_32x32x16_bf16(k0, qfA[0], FZERO, 0, 0, 0);
        f32x16 sB = __builtin_amdgcn_mfma_f32_32x32x16_bf16(k0, qfB[0], FZERO, 0, 0, 0);
        sA = __builtin_amdgcn_mfma_f32_32x32x16_bf16(k1, qfA[1], sA, 0, 0, 0);
        sB = __builtin_amdgcn_mfma_f32_32x32x16_bf16(k1, qfB[1], sB, 0, 0, 0);
        sA = __builtin_amdgcn_mfma_f32_32x32x16_bf16(k2, qfA[2], sA, 0, 0, 0);
        sB = __builtin_amdgcn_mfma_f32_32x32x16_bf16(k2, qfB[2], sB, 0, 0, 0);
        sA = __builtin_amdgcn_mfma_f32_32x32x16_bf16(k3, qfA[3], sA, 0, 0, 0);
        sB = __builtin_amdgcn_mfma_f32_32x32x16_bf16(k3, qfB[3], sB, 0, 0, 0);
        __builtin_amdgcn_sched_barrier(0);
        // ---- S2: V loads + exp/cvt (NO serial lsum adds) ----
        short8 va0 = *(const short8*)(T + 8192 + vofA);
        short8 va1 = *(const short8*)(T + 8192 + vofA + 4096);
        short8 vb0 = *(const short8*)(T + 8192 + vofB);
        short8 vb1 = *(const short8*)(T + 8192 + vofB + 4096);
        unsigned int wA[8], wB[8];
        #pragma unroll
        for (int i = 0; i < 8; ++i) {
            float a0 = __builtin_amdgcn_exp2f(sA[2*i]);
            float a1 = __builtin_amdgcn_exp2f(sA[2*i+1]);
            asm("v_cvt_pk_bf16_f32 %0, %1, %2" : "=v"(wA[i]) : "v"(a0), "v"(a1));
            float b0 = __builtin_amdgcn_exp2f(sB[2*i]);
            float b1 = __builtin_amdgcn_exp2f(sB[2*i+1]);
            asm("v_cvt_pk_bf16_f32 %0, %1, %2" : "=v"(wB[i]) : "v"(b0), "v"(b1));
        }
        asm("v_permlane32_swap_b32 %0, %1" : "+v"(wA[0]), "+v"(wA[2]));
        asm("v_permlane32_swap_b32 %0, %1" : "+v"(wA[1]), "+v"(wA[3]));
        asm("v_permlane32_swap_b32 %0, %1" : "+v"(wA[4]), "+v"(wA[6]));
        asm("v_permlane32_swap_b32 %0, %1" : "+v"(wA[5]), "+v"(wA[7]));
        asm("v_permlane32_swap_b32 %0, %1" : "+v"(wB[0]), "+v"(wB[2]));
        asm("v_permlane32_swap_b32 %0, %1" : "+v"(wB[1]), "+v"(wB[3]));
        asm("v_permlane32_swap_b32 %0, %1" : "+v"(wB[4]), "+v"(wB[6]));
        asm("v_permlane32_swap_b32 %0, %1" : "+v"(wB[5]), "+v"(wB[7]));
        __builtin_amdgcn_sched_barrier(0);
        // ---- S3: PV + lsum MFMAs of BOTH streams ----
        {
            PW paA, pbA, paB, pbB;
            paA.u[0]=wA[0]; paA.u[1]=wA[1]; paA.u[2]=wA[2]; paA.u[3]=wA[3];
            pbA.u[0]=wA[4]; pbA.u[1]=wA[5]; pbA.u[2]=wA[6]; pbA.u[3]=wA[7];
            paB.u[0]=wB[0]; paB.u[1]=wB[1]; paB.u[2]=wB[2]; paB.u[3]=wB[3];
            pbB.u[0]=wB[4]; pbB.u[1]=wB[5]; pbB.u[2]=wB[6]; pbB.u[3]=wB[7];
            __builtin_amdgcn_s_setprio(1);
            oA0 = __builtin_amdgcn_mfma_f32_32x32x16_bf16(va0, paA.s, oA0, 0, 0, 0);
            oB0 = __builtin_amdgcn_mfma_f32_32x32x16_bf16(va0, paB.s, oB0, 0, 0, 0);
            oA1 = __builtin_amdgcn_mfma_f32_32x32x16_bf16(va1, paA.s, oA1, 0, 0, 0);
            oB1 = __builtin_amdgcn_mfma_f32_32x32x16_bf16(va1, paB.s, oB1, 0, 0, 0);
            oLA = __builtin_amdgcn_mfma_f32_32x32x16_bf16(ones, paA.s, oLA, 0, 0, 0);
            oLB = __builtin_amdgcn_mfma_f32_32x32x16_bf16(ones, paB.s, oLB, 0, 0, 0);
            oA0 = __builtin_amdgcn_mfma_f32_32x32x16_bf16(vb0, pbA.s, oA0, 0, 0, 0);
            oB0 = __builtin_amdgcn_mfma_f32_32x32x16_bf16(vb0, pbB.s, oB0, 0, 0, 0);
            oA1 = __builtin_amdgcn_mfma_f32_32x32x16_bf16(vb1, pbA.s, oA1, 0, 0, 0);
            oB1 = __builtin_amdgcn_mfma_f32_32x32x16_bf16(vb1, pbB.s, oB1, 0, 0, 0);
            oLA = __builtin_amdgcn_mfma_f32_32x32x16_bf16(ones, pbA.s, oLA, 0, 0, 0);
            oLB = __builtin_amdgcn_mfma_f32_32x32x16_bf16(ones, pbB.s, oLB, 0, 0, 0);
            __builtin_amdgcn_s_setprio(0);
        }
    };

    // counted-vmcnt deep pipeline: ring of 4 pairs; stage pair p+2 in phase p
    auto runPass = [&]() {
        #pragma unroll 1
        for (int p = 0; p < NT/2; ++p) {
            bool prefetch = (p + 2 < NT/2);
            if (prefetch) {
                int bb0 = (2*p + 4) & 7;
                STAGE(bb0, 2*p + 4);
                STAGE(bb0 + 1, 2*p + 5);
            }
            int ba = (2*p) & 7;
            doTile(L + ba*16384);
            doTile(L + (ba+1)*16384);
            if (prefetch) asm volatile("s_waitcnt vmcnt(4)" ::: "memory");
            else          asm volatile("s_waitcnt vmcnt(0)" ::: "memory");
            __builtin_amdgcn_s_barrier();
            asm volatile("" ::: "memory");
        }
    };

    auto prologue = [&]() {
        STAGE(0, 0); STAGE(1, 1);       // pair 0
        STAGE(2, 2); STAGE(3, 3);       // pair 1
        asm volatile("s_waitcnt vmcnt(4)" ::: "memory");   // pair 0 landed
        __builtin_amdgcn_s_barrier();
        asm volatile("" ::: "memory");
    };

    // ---- pass 1 ----
    prologue();
    runPass();
    float lsA = oLA[0];   // full 32-key per-wave sum (post-permlane P)
    float lsB = oLB[0];
    // ---- pass boundary: combine ks halves, compute state1 for both streams ----
    if (ks == 1) {
        #pragma unroll
        for (int i = 0; i < 8; ++i) {
            unsigned int u;
            asm("v_cvt_pk_bf16_f32 %0, %1, %2" : "=v"(u) : "v"(oA0[2*i]), "v"(oA0[2*i+1]));
            slotA[i*64 + l] = u;
            asm("v_cvt_pk_bf16_f32 %0, %1, %2" : "=v"(u) : "v"(oA1[2*i]), "v"(oA1[2*i+1]));
            slotA[(8+i)*64 + l] = u;
            asm("v_cvt_pk_bf16_f32 %0, %1, %2" : "=v"(u) : "v"(oB0[2*i]), "v"(oB0[2*i+1]));
            slotB[i*64 + l] = u;
            asm("v_cvt_pk_bf16_f32 %0, %1, %2" : "=v"(u) : "v"(oB1[2*i]), "v"(oB1[2*i+1]));
            slotB[(8+i)*64 + l] = u;
        }
        slsA[l] = lsA;
        slsB[l] = lsB;
        asm volatile("s_waitcnt lgkmcnt(0)" ::: "memory");
    }
    __builtin_amdgcn_s_barrier();
    asm volatile("" ::: "memory");
    if (ks == 0) {
        #pragma unroll
        for (int i = 0; i < 8; ++i) {
            unsigned int u = slotA[i*64 + l];
            oA0[2*i]   += __uint_as_float(u << 16);
            oA0[2*i+1] += __uint_as_float(u & 0xffff0000u);
            u = slotA[(8+i)*64 + l];
            oA1[2*i]   += __uint_as_float(u << 16);
            oA1[2*i+1] += __uint_as_float(u & 0xffff0000u);
            u = slotB[i*64 + l];
            oB0[2*i]   += __uint_as_float(u << 16);
            oB0[2*i+1] += __uint_as_float(u & 0xffff0000u);
            u = slotB[(8+i)*64 + l];
            oB1[2*i]   += __uint_as_float(u << 16);
            oB1[2*i+1] += __uint_as_float(u & 0xffff0000u);
        }
        float oscA = LOG2E / (lsA + slsA[l]);
        float oscB = LOG2E / (lsB + slsB[l]);
        unsigned int w0[8], w1[8], w2[8], w3[8];
        #pragma unroll
        for (int i = 0; i < 8; ++i) {
            float a0 = oA0[2*i]*oscA, a1 = oA0[2*i+1]*oscA;
            asm("v_cvt_pk_bf16_f32 %0, %1, %2" : "=v"(w0[i]) : "v"(a0), "v"(a1));
            float b0 = oA1[2*i]*oscA, b1 = oA1[2*i+1]*oscA;
            asm("v_cvt_pk_bf16_f32 %0, %1, %2" : "=v"(w1[i]) : "v"(b0), "v"(b1));
            float c0 = oB0[2*i]*oscB, c1 = oB0[2*i+1]*oscB;
            asm("v_cvt_pk_bf16_f32 %0, %1, %2" : "=v"(w2[i]) : "v"(c0), "v"(c1));
            float d0 = oB1[2*i]*oscB, d1 = oB1[2*i+1]*oscB;
            asm("v_cvt_pk_bf16_f32 %0, %1, %2" : "=v"(w3[i]) : "v"(d0), "v"(d1));
        }
        asm volatile("v_permlane32_swap_b32 %0, %1" : "+v"(w0[0]), "+v"(w0[2]));
        asm volatile("v_permlane32_swap_b32 %0, %1" : "+v"(w0[1]), "+v"(w0[3]));
        asm volatile("v_permlane32_swap_b32 %0, %1" : "+v"(w0[4]), "+v"(w0[6]));
        asm volatile("v_permlane32_swap_b32 %0, %1" : "+v"(w0[5]), "+v"(w0[7]));
        asm volatile("v_permlane32_swap_b32 %0, %1" : "+v"(w1[0]), "+v"(w1[2]));
        asm volatile("v_permlane32_swap_b32 %0, %1" : "+v"(w1[1]), "+v"(w1[3]));
        asm volatile("v_permlane32_swap_b32 %0, %1" : "+v"(w1[4]), "+v"(w1[6]));
        asm volatile("v_permlane32_swap_b32 %0, %1" : "+v"(w1[5]), "+v"(w1[7]));
        asm volatile("v_permlane32_swap_b32 %0, %1" : "+v"(w2[0]), "+v"(w2[2]));
        asm volatile("v_permlane32_swap_b32 %0, %1" : "+v"(w2[1]), "+v"(w2[3]));
        asm volatile("v_permlane32_swap_b32 %0, %1" : "+v"(w2[4]), "+v"(w2[6]));
        asm volatile("v_permlane32_swap_b32 %0, %1" : "+v"(w2[5]), "+v"(w2[7]));
        asm volatile("v_permlane32_swap_b32 %0, %1" : "+v"(w3[0]), "+v"(w3[2]));
        asm volatile("v_permlane32_swap_b32 %0, %1" : "+v"(w3[1]), "+v"(w3[3]));
        asm volatile("v_permlane32_swap_b32 %0, %1" : "+v"(w3[4]), "+v"(w3[6]));
        asm volatile("v_permlane32_swap_b32 %0, %1" : "+v"(w3[5]), "+v"(w3[7]));
        PW pa;
        pa.u[0]=w0[0]; pa.u[1]=w0[1]; pa.u[2]=w0[2]; pa.u[3]=w0[3]; qfA[0]=pa.s;
        pa.u[0]=w0[4]; pa.u[1]=w0[5]; pa.u[2]=w0[6]; pa.u[3]=w0[7]; qfA[1]=pa.s;
        pa.u[0]=w1[0]; pa.u[1]=w1[1]; pa.u[2]=w1[2]; pa.u[3]=w1[3]; qfA[2]=pa.s;
        pa.u[0]=w1[4]; pa.u[1]=w1[5]; pa.u[2]=w1[6]; pa.u[3]=w1[7]; qfA[3]=pa.s;
        pa.u[0]=w2[0]; pa.u[1]=w2[1]; pa.u[2]=w2[2]; pa.u[3]=w2[3]; qfB[0]=pa.s;
        pa.u[0]=w2[4]; pa.u[1]=w2[5]; pa.u[2]=w2[6]; pa.u[3]=w2[7]; qfB[1]=pa.s;
        pa.u[0]=w3[0]; pa.u[1]=w3[1]; pa.u[2]=w3[2]; pa.u[3]=w3[3]; qfB[2]=pa.s;
        pa.u[0]=w3[4]; pa.u[1]=w3[5]; pa.u[2]=w3[6]; pa.u[3]=w3[7]; qfB[3]=pa.s;
        #pragma unroll
        for (int i = 0; i < 8; ++i) {
            slotA[i*64 + l] = w0[i];
            slotA[(8+i)*64 + l] = w1[i];
            slotB[i*64 + l] = w2[i];
            slotB[(8+i)*64 + l] = w3[i];
        }
        asm volatile("s_waitcnt lgkmcnt(0)" ::: "memory");
    }
    __builtin_amdgcn_s_barrier();
    asm volatile("" ::: "memory");
    if (ks == 1) {
        PW pa;
        pa.u[0]=slotA[0*64+l]; pa.u[1]=slotA[1*64+l]; pa.u[2]=slotA[2*64+l]; pa.u[3]=slotA[3*64+l]; qfA[0]=pa.s;
        pa.u[0]=slotA[4*64+l]; pa.u[1]=slotA[5*64+l]; pa.u[2]=slotA[6*64+l]; pa.u[3]=slotA[7*64+l]; qfA[1]=pa.s;
        pa.u[0]=slotA[8*64+l]; pa.u[1]=slotA[9*64+l]; pa.u[2]=slotA[10*64+l]; pa.u[3]=slotA[11*64+l]; qfA[2]=pa.s;
        pa.u[0]=slotA[12*64+l]; pa.u[1]=slotA[13*64+l]; pa.u[2]=slotA[14*64+l]; pa.u[3]=slotA[15*64+l]; qfA[3]=pa.s;
        pa.u[0]=slotB[0*64+l]; pa.u[1]=slotB[1*64+l]; pa.u[2]=slotB[2*64+l]; pa.u[3]=slotB[3*64+l]; qfB[0]=pa.s;
        pa.u[0]=slotB[4*64+l]; pa.u[1]=slotB[5*64+l]; pa.u[2]=slotB[6*64+l]; pa.u[3]=slotB[7*64+l]; qfB[1]=pa.s;
        pa.u[0]=slotB[8*64+l]; pa.u[1]=slotB[9*64+l]; pa.u[2]=slotB[10*64+l]; pa.u[3]=slotB[11*64+l]; qfB[2]=pa.s;
        pa.u[0]=slotB[12*64+l]; pa.u[1]=slotB[13*64+l]; pa.u[2]=slotB[14*64+l]; pa.u[3]=slotB[15*64+l]; qfB[3]=pa.s;
    }
    asm volatile("s_waitcnt lgkmcnt(0)" ::: "memory");
    __builtin_amdgcn_s_barrier();
    asm volatile("" ::: "memory");
    oA0 = 0.0f; oA1 = 0.0f; oB0 = 0.0f; oB1 = 0.0f; oLA = 0.0f; oLB = 0.0f;
    // ---- pass 2 ----
    prologue();
    runPass();
    lsA = oLA[0];
    lsB = oLB[0];
    // ---- final combine + output ----
    if (ks == 1) {
        #pragma unroll
        for (int i = 0; i < 8; ++i) {
            unsigned int u;
            asm("v_cvt_pk_bf16_f32 %0, %1, %2" : "=v"(u) : "v"(oA0[2*i]), "v"(oA0[2*i+1]));
            slotA[i*64 + l] = u;
            asm("v_cvt_pk_bf16_f32 %0, %1, %2" : "=v"(u) : "v"(oA1[2*i]), "v"(oA1[2*i+1]));
            slotA[(8+i)*64 + l] = u;
            asm("v_cvt_pk_bf16_f32 %0, %1, %2" : "=v"(u) : "v"(oB0[2*i]), "v"(oB0[2*i+1]));
            slotB[i*64 + l] = u;
            asm("v_cvt_pk_bf16_f32 %0, %1, %2" : "=v"(u) : "v"(oB1[2*i]), "v"(oB1[2*i+1]));
            slotB[(8+i)*64 + l] = u;
        }
        slsA[l] = lsA;
        slsB[l] = lsB;
        asm volatile("s_waitcnt lgkmcnt(0)" ::: "memory");
    }
    __builtin_amdgcn_s_barrier();
    asm volatile("" ::: "memory");
    if (ks == 0) {
        #pragma unroll
        for (int i = 0; i < 8; ++i) {
            unsigned int u = slotA[i*64 + l];
            oA0[2*i]   += __uint_as_float(u << 16);
            oA0[2*i+1] += __uint_as_float(u & 0xffff0000u);
            u = slotA[(8+i)*64 + l];
            oA1[2*i]   += __uint_as_float(u << 16);
            oA1[2*i+1] += __uint_as_float(u & 0xffff0000u);
            u = slotB[i*64 + l];
            oB0[2*i]   += __uint_as_float(u << 16);
            oB0[2*i+1] += __uint_as_float(u & 0xffff0000u);
            u = slotB[(8+i)*64 + l];
            oB1[2*i]   += __uint_as_float(u << 16);
            oB1[2*i+1] += __uint_as_float(u & 0xffff0000u);
        }
        float oscA = 1.0f / (lsA + slsA[l]);
        float oscB = 1.0f / (lsB + slsB[l]);
        int bb = bh >> 4, hh = bh & 15;
        int rowA = q0 + wq*64 + q;
        unsigned short* orowA = outp + ((size_t)bb*SEQLEN + rowA)*HDIM + hh*HEADD;
        unsigned short* orowB = orowA + 32*HDIM;
        const int dtab[8] = {0,2,8,10,16,18,24,26};
        #pragma unroll
        for (int i = 0; i < 8; ++i) {
            int d = dtab[i] + 4*hi;
            unsigned int wv;
            float a0 = oA0[2*i]*oscA, a1 = oA0[2*i+1]*oscA;
            asm("v_cvt_pk_bf16_f32 %0, %1, %2" : "=v"(wv) : "v"(a0), "v"(a1));
            *(unsigned int*)(orowA + d) = wv;
            float b0 = oA1[2*i]*oscA, b1 = oA1[2*i+1]*oscA;
            asm("v_cvt_pk_bf16_f32 %0, %1, %2" : "=v"(wv) : "v"(b0), "v"(b1));
            *(unsigned int*)(orowA + 32 + d) = wv;
            float c0 = oB0[2*i]*oscB, c1 = oB0[2*i+1]*oscB;
            asm("v_cvt_pk_bf16_f32 %0, %1, %2" : "=v"(wv) : "v"(c0), "v"(c1));
            *(unsigned int*)(orowB + d) = wv;
            float d0 = oB1[2*i]*oscB, d1 = oB1[2*i+1]*oscB;
            asm("v_cvt_pk_bf16_f32 %0, %1, %2" : "=v"(wv) : "v"(d0), "v"(d1));
            *(unsigned int*)(orowB + 32 + d) = wv;
        }
    }
}

extern "C" void kernel_launch(void* const* d_in, const int* in_sizes, int n_in,
                              void* d_out, int out_size, void* d_ws, size_t ws_size,
                              hipStream_t stream) {
    const float* hs = (const float*)d_in[0];
    const float* Wq = (const float*)d_in[1];
    const float* bq = (const float*)d_in[2];
    const float* Wk = (const float*)d_in[3];
    const float* bk = (const float*)d_in[4];
    const float* Wv = (const float*)d_in[5];
    const float* bv = (const float*)d_in[6];
    const float* Wo = (const float*)d_in[7];
    const float* bo = (const float*)d_in[8];
    const float* lw = (const float*)d_in[9];
    const float* lb = (const float*)d_in[10];
    unsigned short* ws16 = (unsigned short*)d_ws;
    const size_t NE = (size_t)NROWS * HDIM;
    const size_t WE = (size_t)HDIM * HDIM;
    unsigned short* xn  = ws16;
    unsigned short* Wtq = xn + NE;       // Wtq/Wtk/Wtv/Wto contiguous
    unsigned short* Wto = Wtq + 3*WE;
    unsigned short* qb  = Wtq + 4*WE;
    unsigned short* kb  = qb + NE;
    unsigned short* vt  = kb + NE;
    unsigned short* s2  = vt + NE;

    ln_kernel<<<NROWS, 256, 0, stream>>>(hs, lw, lb, xn);
    wconv_kernel<<<dim3(HDIM/64, HDIM/64, 4), 256, 0, stream>>>(Wq, Wk, Wv, Wo, Wtq);
    gemm_qkv_kernel<<<dim3(NROWS/128, 24), 256, 0, stream>>>(xn, Wtq, bq, bk, bv, qb, kb, vt);
    attn_fused_kernel<<<NBH*8, 512, 0, stream>>>(qb, kb, vt, s2);
    gemm_o_kernel<<<dim3(NROWS/128, HDIM/64), 256, 0, stream>>>(s2, Wto, bo, hs, (float*)d_out);
}

// Round 18
// 150.320 us; speedup vs baseline: 1.0649x; 1.0349x over previous
//
#include <hip/hip_runtime.h>
#include <hip/hip_bf16.h>
#include <math.h>

#define HDIM 1024
#define NHEADS 16
#define HEADD 64
#define SEQLEN 2048
#define NBATCH 2
#define NROWS (NBATCH*SEQLEN)
#define NBH (NBATCH*NHEADS)
#define LOG2E 1.44269504f
#define NT 32   // 64-key tiles per pass

typedef float f32x4 __attribute__((ext_vector_type(4)));
typedef float f32x16 __attribute__((ext_vector_type(16)));
typedef short short8 __attribute__((ext_vector_type(8)));
typedef unsigned short us4v __attribute__((ext_vector_type(4)));

#define GLOBAL_AS __attribute__((address_space(1)))
#define LDS_AS __attribute__((address_space(3)))

union F4 { float4 v; float f[4]; };
union PW { unsigned int u[4]; short8 s; };

static __device__ __forceinline__ unsigned short f2bf(float x) {
    __hip_bfloat16 h = __float2bfloat16(x);
    return *(unsigned short*)&h;
}

// -------- merged prep: blocks [0,NROWS) = LayerNorm row; rest = wconv tile --------
__global__ __launch_bounds__(256) void prep_kernel(
        const float* __restrict__ x, const float* __restrict__ lw,
        const float* __restrict__ lb, unsigned short* __restrict__ xn,
        const float* __restrict__ W0, const float* __restrict__ W1,
        const float* __restrict__ W2, const float* __restrict__ W3,
        unsigned short* __restrict__ WtBase) {
    __shared__ unsigned short T[64*72];
    __shared__ float red[8];
    int bid = blockIdx.x;
    int t = threadIdx.x;
    if (bid < NROWS) {
        int row = bid;
        F4 vv; vv.v = ((const float4*)(x + (size_t)row*HDIM))[t];
        float s  = vv.f[0]+vv.f[1]+vv.f[2]+vv.f[3];
        float ss = vv.f[0]*vv.f[0]+vv.f[1]*vv.f[1]+vv.f[2]*vv.f[2]+vv.f[3]*vv.f[3];
        #pragma unroll
        for (int off = 32; off > 0; off >>= 1) {
            s  += __shfl_xor(s, off);
            ss += __shfl_xor(ss, off);
        }
        int wid = t >> 6;
        if ((t & 63) == 0) { red[wid] = s; red[wid+4] = ss; }
        __syncthreads();
        s  = red[0]+red[1]+red[2]+red[3];
        ss = red[4]+red[5]+red[6]+red[7];
        float mean = s * (1.0f/HDIM);
        float var  = ss * (1.0f/HDIM) - mean*mean;
        float rstd = rsqrtf(var + 1e-5f);
        F4 wv; wv.v = ((const float4*)lw)[t];
        F4 bv; bv.v = ((const float4*)lb)[t];
        us4v o;
        #pragma unroll
        for (int j = 0; j < 4; ++j)
            o[j] = f2bf((vv.f[j]-mean)*rstd*wv.f[j] + bv.f[j]);
        *(us4v*)(xn + (size_t)row*HDIM + t*4) = o;
    } else {
        int wb = bid - NROWS;             // 0..1023
        int z = wb >> 8;                  // matrix
        int rem = wb & 255;
        int k0 = (rem >> 4)*64, n0 = (rem & 15)*64;
        const float* W = (z == 0) ? W0 : (z == 1) ? W1 : (z == 2) ? W2 : W3;
        unsigned short* Wt = WtBase + (size_t)z*HDIM*HDIM;
        #pragma unroll
        for (int it = 0; it < 4; ++it) {
            int r = (t>>4) + it*16;
            int c = (t&15)*4;
            F4 xv; xv.v = *(const float4*)(W + (size_t)(k0+r)*HDIM + n0 + c);
            #pragma unroll
            for (int j = 0; j < 4; ++j) T[(c+j)*72 + r] = f2bf(xv.f[j]);
        }
        __syncthreads();
        #pragma unroll
        for (int it = 0; it < 2; ++it) {
            int n = (t>>3) + it*32;
            int ch = t&7;
            short8 rowv = *(const short8*)(T + n*72 + ch*8);
            *(short8*)(Wt + (size_t)(n0+n)*HDIM + k0 + ch*8) = rowv;
        }
    }
}

// ------------- fused QKV GEMM: mat = blockIdx.y>>3 (0:Q 1:K 2:V) -------------
__global__ __launch_bounds__(256) void gemm_qkv_kernel(
        const unsigned short* __restrict__ A,
        const unsigned short* __restrict__ WtBase,
        const float* __restrict__ bq, const float* __restrict__ bk,
        const float* __restrict__ bv,
        unsigned short* __restrict__ qb, unsigned short* __restrict__ kb,
        unsigned short* __restrict__ vt) {
    __shared__ unsigned short As[2][128*64];
    __shared__ unsigned short Bs[2][128*64];
    int m0 = blockIdx.x * 128;
    int yy = blockIdx.y;
    int mat = yy >> 3;
    int n0 = (yy & 7) * 128;
    const unsigned short* Wt = WtBase + (size_t)mat*HDIM*HDIM;
    const float* bias = (mat == 0) ? bq : (mat == 1) ? bk : bv;
    int t = threadIdx.x;
    int wid = t >> 6, l = t & 63;
    int wm = wid >> 1, wn = wid & 1;
    int lq = l & 15, g = l >> 4;
    f32x4 acc[4][4];
    #pragma unroll
    for (int mi = 0; mi < 4; ++mi)
        #pragma unroll
        for (int ni = 0; ni < 4; ++ni) acc[mi][ni] = 0.0f;

    auto STAGE = [&](int b, int k0) {
        #pragma unroll
        for (int i = 0; i < 4; ++i) {
            int idx = t + 256*i;
            int r = idx >> 3, ch = idx & 7;
            int gch = ch ^ (r & 7);
            __builtin_amdgcn_global_load_lds(
                (const GLOBAL_AS void*)(A + (size_t)(m0+r)*HDIM + k0 + gch*8),
                (LDS_AS void*)((char*)&As[b][0] + idx*16), 16, 0, 0);
            __builtin_amdgcn_global_load_lds(
                (const GLOBAL_AS void*)(Wt + (size_t)(n0+r)*HDIM + k0 + gch*8),
                (LDS_AS void*)((char*)&Bs[b][0] + idx*16), 16, 0, 0);
        }
    };

    STAGE(0, 0);
    asm volatile("s_waitcnt vmcnt(0)" ::: "memory");
    __builtin_amdgcn_s_barrier();
    asm volatile("" ::: "memory");
    int buf = 0;
    for (int ks = 0; ks < 16; ++ks) {
        if (ks < 15) STAGE(buf^1, (ks+1)*64);
        const char* Ab = (const char*)&As[buf][0];
        const char* Bb = (const char*)&Bs[buf][0];
        #pragma unroll
        for (int kc = 0; kc < 2; ++kc) {
            short8 af[4], bf[4];
            #pragma unroll
            for (int mi = 0; mi < 4; ++mi) {
                int r = wm*64 + mi*16 + lq;
                af[mi] = *(const short8*)(Ab + r*128 + (((kc*4+g) ^ (r&7))<<4));
            }
            #pragma unroll
            for (int ni = 0; ni < 4; ++ni) {
                int r = wn*64 + ni*16 + lq;
                bf[ni] = *(const short8*)(Bb + r*128 + (((kc*4+g) ^ (r&7))<<4));
            }
            #pragma unroll
            for (int mi = 0; mi < 4; ++mi)
                #pragma unroll
                for (int ni = 0; ni < 4; ++ni)
                    acc[mi][ni] = __builtin_amdgcn_mfma_f32_16x16x32_bf16(
                        af[mi], bf[ni], acc[mi][ni], 0, 0, 0);
        }
        asm volatile("s_waitcnt vmcnt(0)" ::: "memory");
        __builtin_amdgcn_s_barrier();
        asm volatile("" ::: "memory");
        buf ^= 1;
    }
    float bvv[4];
    #pragma unroll
    for (int ni = 0; ni < 4; ++ni) bvv[ni] = bias[n0 + wn*64 + ni*16 + lq];
    #pragma unroll
    for (int mi = 0; mi < 4; ++mi)
        #pragma unroll
        for (int ni = 0; ni < 4; ++ni)
            #pragma unroll
            for (int i = 0; i < 4; ++i) acc[mi][ni][i] += bvv[ni];
    int h = (n0 >> 6) + wn;
    if (mat <= 1) {
        unsigned short* outp = (mat == 0) ? qb : kb;
        float oscale = (mat == 0) ? LOG2E : 1.0f;
        #pragma unroll
        for (int mi = 0; mi < 4; ++mi) {
            f32x4 ss = 0.0f;
            #pragma unroll
            for (int ni = 0; ni < 4; ++ni)
                #pragma unroll
                for (int i = 0; i < 4; ++i) ss[i] += acc[mi][ni][i]*acc[mi][ni][i];
            #pragma unroll
            for (int off = 1; off < 16; off <<= 1)
                #pragma unroll
                for (int i = 0; i < 4; ++i) ss[i] += __shfl_xor(ss[i], off);
            #pragma unroll
            for (int i = 0; i < 4; ++i) {
                float sc = oscale / fmaxf(sqrtf(ss[i]), 1e-12f);
                int m = m0 + wm*64 + mi*16 + g*4 + i;
                int bb = m >> 11, sq = m & (SEQLEN-1);
                unsigned short* orow = outp
                    + ((size_t)(bb*NHEADS + h)*SEQLEN + sq)*HEADD;
                #pragma unroll
                for (int ni = 0; ni < 4; ++ni)
                    orow[ni*16 + lq] = f2bf(acc[mi][ni][i] * sc);
            }
        }
    } else {
        #pragma unroll
        for (int mi = 0; mi < 4; ++mi) {
            int m = m0 + wm*64 + mi*16 + g*4;
            int bb = m >> 11, sq = m & (SEQLEN-1);
            #pragma unroll
            for (int ni = 0; ni < 4; ++ni) {
                int d = ni*16 + lq;
                us4v pk;
                #pragma unroll
                for (int i = 0; i < 4; ++i) pk[i] = f2bf(acc[mi][ni][i]);
                *(us4v*)(vt + ((size_t)(bb*NHEADS + h)*HEADD + d)*SEQLEN + sq) = pk;
            }
        }
    }
}

// --------- O-projection GEMM 128x64 tile: out = A@Wt^T + bias + residual ---------
__global__ __launch_bounds__(256) void gemm_o_kernel(
        const unsigned short* __restrict__ A,
        const unsigned short* __restrict__ Wt,
        const float* __restrict__ bias,
        const float* __restrict__ residual,
        float* __restrict__ out) {
    __shared__ unsigned short As[2][128*64];
    __shared__ unsigned short Bs[2][64*64];
    int m0 = blockIdx.x * 128;
    int n0 = blockIdx.y * 64;
    int t = threadIdx.x;
    int wid = t >> 6, l = t & 63;
    int wm = wid >> 1, wn = wid & 1;
    int lq = l & 15, g = l >> 4;
    f32x4 acc[4][2];
    #pragma unroll
    for (int mi = 0; mi < 4; ++mi)
        #pragma unroll
        for (int ni = 0; ni < 2; ++ni) acc[mi][ni] = 0.0f;

    auto STAGE = [&](int b, int k0) {
        #pragma unroll
        for (int i = 0; i < 4; ++i) {
            int idx = t + 256*i;
            int r = idx >> 3, ch = idx & 7;
            int gch = ch ^ (r & 7);
            __builtin_amdgcn_global_load_lds(
                (const GLOBAL_AS void*)(A + (size_t)(m0+r)*HDIM + k0 + gch*8),
                (LDS_AS void*)((char*)&As[b][0] + idx*16), 16, 0, 0);
        }
        #pragma unroll
        for (int i = 0; i < 2; ++i) {
            int idx = t + 256*i;
            int r = idx >> 3, ch = idx & 7;
            int gch = ch ^ (r & 7);
            __builtin_amdgcn_global_load_lds(
                (const GLOBAL_AS void*)(Wt + (size_t)(n0+r)*HDIM + k0 + gch*8),
                (LDS_AS void*)((char*)&Bs[b][0] + idx*16), 16, 0, 0);
        }
    };

    STAGE(0, 0);
    asm volatile("s_waitcnt vmcnt(0)" ::: "memory");
    __builtin_amdgcn_s_barrier();
    asm volatile("" ::: "memory");
    int buf = 0;
    for (int ks = 0; ks < 16; ++ks) {
        if (ks < 15) STAGE(buf^1, (ks+1)*64);
        const char* Ab = (const char*)&As[buf][0];
        const char* Bb = (const char*)&Bs[buf][0];
        #pragma unroll
        for (int kc = 0; kc < 2; ++kc) {
            short8 af[4], bf[2];
            #pragma unroll
            for (int mi = 0; mi < 4; ++mi) {
                int r = wm*64 + mi*16 + lq;
                af[mi] = *(const short8*)(Ab + r*128 + (((kc*4+g) ^ (r&7))<<4));
            }
            #pragma unroll
            for (int ni = 0; ni < 2; ++ni) {
                int r = wn*32 + ni*16 + lq;
                bf[ni] = *(const short8*)(Bb + r*128 + (((kc*4+g) ^ (r&7))<<4));
            }
            #pragma unroll
            for (int mi = 0; mi < 4; ++mi)
                #pragma unroll
                for (int ni = 0; ni < 2; ++ni)
                    acc[mi][ni] = __builtin_amdgcn_mfma_f32_16x16x32_bf16(
                        af[mi], bf[ni], acc[mi][ni], 0, 0, 0);
        }
        asm volatile("s_waitcnt vmcnt(0)" ::: "memory");
        __builtin_amdgcn_s_barrier();
        asm volatile("" ::: "memory");
        buf ^= 1;
    }
    float bvv[2];
    #pragma unroll
    for (int ni = 0; ni < 2; ++ni) bvv[ni] = bias[n0 + wn*32 + ni*16 + lq];
    #pragma unroll
    for (int mi = 0; mi < 4; ++mi)
        #pragma unroll
        for (int i = 0; i < 4; ++i) {
            int m = m0 + wm*64 + mi*16 + g*4 + i;
            float* orow = out + (size_t)m*HDIM;
            const float* rrow = residual + (size_t)m*HDIM;
            #pragma unroll
            for (int ni = 0; ni < 2; ++ni) {
                int n = n0 + wn*32 + ni*16 + lq;
                orow[n] = acc[mi][ni][i] + bvv[ni] + rrow[n];
            }
        }
}

// ------- fused 2-step Hopfield attention (proven-best R15 configuration) -------
// 512 threads = 4 wq x 2 ks waves; wave: 64 q (streams A,B) x 32 keys.
// 8 staging buffers (128 KB), counted vmcnt(4): loads span two phases+barriers.
__global__ __launch_bounds__(512, 2) void attn_fused_kernel(
        const unsigned short* __restrict__ qg, const unsigned short* __restrict__ kg,
        const unsigned short* __restrict__ vtg, unsigned short* __restrict__ outp) {
    __shared__ char L[8*16384];   // 128 KiB: ring of 4 tile-pairs
    int b = blockIdx.x;
    int bh = (b & 7)*4 + ((b >> 3) & 3);   // 4 heads per XCD
    int q0 = (b >> 5) * 256;               // 256 q-rows per block
    int t = threadIdx.x;
    int wid = t >> 6, l = t & 63;
    int wq = wid >> 1, ks = wid & 1;
    int q = l & 31, hi = l >> 5, r7 = q & 7;
    short8 qfA[4], qfB[4];
    {
        const unsigned short* qrowA = qg + ((size_t)bh*SEQLEN + q0 + wq*64 + q)*HEADD;
        const unsigned short* qrowB = qrowA + 32*HEADD;
        #pragma unroll
        for (int dc = 0; dc < 4; ++dc) {
            qfA[dc] = *(const short8*)(qrowA + dc*16 + hi*8);
            qfB[dc] = *(const short8*)(qrowB + dc*16 + hi*8);
        }
    }
    int koffK0 = q*128 + (((0 + hi) ^ r7) << 4) + ks*4096;
    int koffK1 = q*128 + (((2 + hi) ^ r7) << 4) + ks*4096;
    int koffK2 = q*128 + (((4 + hi) ^ r7) << 4) + ks*4096;
    int koffK3 = q*128 + (((6 + hi) ^ r7) << 4) + ks*4096;
    int vofA = q*128 + (((4*ks + hi) ^ r7) << 4);
    int vofB = q*128 + (((4*ks + 2 + hi) ^ r7) << 4);

    f32x16 oA0 = 0.0f, oA1 = 0.0f, oB0 = 0.0f, oB1 = 0.0f;
    float lsA = 0.0f, lsB = 0.0f;
    const unsigned short* Kg = kg + (size_t)bh*SEQLEN*HEADD;
    const unsigned short* Vg = vtg + (size_t)bh*HEADD*SEQLEN;
    unsigned int* slotA = (unsigned int*)(L + wq*4096);            // buf0
    unsigned int* slotB = (unsigned int*)(L + 16384 + wq*4096);    // buf1
    float* slsA = (float*)(L + 32768 + wq*512);                    // buf2 front
    float* slsB = slsA + 64;

    int sr = t >> 3, sch = t & 7;
    int sgch = sch ^ (sr & 7);
    const unsigned short* Ksrc = Kg + sr*HEADD + sgch*8;
    const unsigned short* Vsrc = Vg + (size_t)sr*SEQLEN + sgch*8;
    auto STAGE = [&](int buf, int kt) {
        __builtin_amdgcn_global_load_lds(
            (const GLOBAL_AS void*)(Ksrc + (size_t)kt*4096),
            (LDS_AS void*)(L + buf*16384 + t*16), 16, 0, 0);
        __builtin_amdgcn_global_load_lds(
            (const GLOBAL_AS void*)(Vsrc + kt*64),
            (LDS_AS void*)(L + buf*16384 + 8192 + t*16), 16, 0, 0);
    };

    auto doTile = [&](const char* T) {
        // ---- S1: K loads + QK of BOTH streams ----
        short8 k0 = *(const short8*)(T + koffK0);
        short8 k1 = *(const short8*)(T + koffK1);
        short8 k2 = *(const short8*)(T + koffK2);
        short8 k3 = *(const short8*)(T + koffK3);
        f32x16 sA = 0.0f, sB = 0.0f;
        sA = __builtin_amdgcn_mfma_f32_32x32x16_bf16(k0, qfA[0], sA, 0, 0, 0);
        sB = __builtin_amdgcn_mfma_f32_32x32x16_bf16(k0, qfB[0], sB, 0, 0, 0);
        sA = __builtin_amdgcn_mfma_f32_32x32x16_bf16(k1, qfA[1], sA, 0, 0, 0);
        sB = __builtin_amdgcn_mfma_f32_32x32x16_bf16(k1, qfB[1], sB, 0, 0, 0);
        sA = __builtin_amdgcn_mfma_f32_32x32x16_bf16(k2, qfA[2], sA, 0, 0, 0);
        sB = __builtin_amdgcn_mfma_f32_32x32x16_bf16(k2, qfB[2], sB, 0, 0, 0);
        sA = __builtin_amdgcn_mfma_f32_32x32x16_bf16(k3, qfA[3], sA, 0, 0, 0);
        sB = __builtin_amdgcn_mfma_f32_32x32x16_bf16(k3, qfB[3], sB, 0, 0, 0);
        __builtin_amdgcn_sched_barrier(0);
        // ---- S2: V loads + softmax of BOTH streams ----
        short8 va0 = *(const short8*)(T + 8192 + vofA);
        short8 va1 = *(const short8*)(T + 8192 + vofA + 4096);
        short8 vb0 = *(const short8*)(T + 8192 + vofB);
        short8 vb1 = *(const short8*)(T + 8192 + vofB + 4096);
        unsigned int wA[8], wB[8];
        float pA = 0.0f, pB = 0.0f;
        #pragma unroll
        for (int i = 0; i < 8; ++i) {
            float a0 = __builtin_amdgcn_exp2f(sA[2*i]);
            float a1 = __builtin_amdgcn_exp2f(sA[2*i+1]);
            pA += a0 + a1;
            asm("v_cvt_pk_bf16_f32 %0, %1, %2" : "=v"(wA[i]) : "v"(a0), "v"(a1));
            float b0 = __builtin_amdgcn_exp2f(sB[2*i]);
            float b1 = __builtin_amdgcn_exp2f(sB[2*i+1]);
            pB += b0 + b1;
            asm("v_cvt_pk_bf16_f32 %0, %1, %2" : "=v"(wB[i]) : "v"(b0), "v"(b1));
        }
        lsA += pA; lsB += pB;
        asm("v_permlane32_swap_b32 %0, %1" : "+v"(wA[0]), "+v"(wA[2]));
        asm("v_permlane32_swap_b32 %0, %1" : "+v"(wA[1]), "+v"(wA[3]));
        asm("v_permlane32_swap_b32 %0, %1" : "+v"(wA[4]), "+v"(wA[6]));
        asm("v_permlane32_swap_b32 %0, %1" : "+v"(wA[5]), "+v"(wA[7]));
        asm("v_permlane32_swap_b32 %0, %1" : "+v"(wB[0]), "+v"(wB[2]));
        asm("v_permlane32_swap_b32 %0, %1" : "+v"(wB[1]), "+v"(wB[3]));
        asm("v_permlane32_swap_b32 %0, %1" : "+v"(wB[4]), "+v"(wB[6]));
        asm("v_permlane32_swap_b32 %0, %1" : "+v"(wB[5]), "+v"(wB[7]));
        __builtin_amdgcn_sched_barrier(0);
        // ---- S3: PV of BOTH streams ----
        {
            PW paA, pbA, paB, pbB;
            paA.u[0]=wA[0]; paA.u[1]=wA[1]; paA.u[2]=wA[2]; paA.u[3]=wA[3];
            pbA.u[0]=wA[4]; pbA.u[1]=wA[5]; pbA.u[2]=wA[6]; pbA.u[3]=wA[7];
            paB.u[0]=wB[0]; paB.u[1]=wB[1]; paB.u[2]=wB[2]; paB.u[3]=wB[3];
            pbB.u[0]=wB[4]; pbB.u[1]=wB[5]; pbB.u[2]=wB[6]; pbB.u[3]=wB[7];
            __builtin_amdgcn_s_setprio(1);
            oA0 = __builtin_amdgcn_mfma_f32_32x32x16_bf16(va0, paA.s, oA0, 0, 0, 0);
            oB0 = __builtin_amdgcn_mfma_f32_32x32x16_bf16(va0, paB.s, oB0, 0, 0, 0);
            oA1 = __builtin_amdgcn_mfma_f32_32x32x16_bf16(va1, paA.s, oA1, 0, 0, 0);
            oB1 = __builtin_amdgcn_mfma_f32_32x32x16_bf16(va1, paB.s, oB1, 0, 0, 0);
            oA0 = __builtin_amdgcn_mfma_f32_32x32x16_bf16(vb0, pbA.s, oA0, 0, 0, 0);
            oB0 = __builtin_amdgcn_mfma_f32_32x32x16_bf16(vb0, pbB.s, oB0, 0, 0, 0);
            oA1 = __builtin_amdgcn_mfma_f32_32x32x16_bf16(vb1, pbA.s, oA1, 0, 0, 0);
            oB1 = __builtin_amdgcn_mfma_f32_32x32x16_bf16(vb1, pbB.s, oB1, 0, 0, 0);
            __builtin_amdgcn_s_setprio(0);
        }
    };

    // counted-vmcnt deep pipeline: ring of 4 pairs; stage pair p+2 in phase p
    auto runPass = [&]() {
        #pragma unroll 1
        for (int p = 0; p < NT/2; ++p) {
            bool prefetch = (p + 2 < NT/2);
            if (prefetch) {
                int bb0 = (2*p + 4) & 7;
                STAGE(bb0, 2*p + 4);
                STAGE(bb0 + 1, 2*p + 5);
            }
            int ba = (2*p) & 7;
            doTile(L + ba*16384);
            doTile(L + (ba+1)*16384);
            if (prefetch) asm volatile("s_waitcnt vmcnt(4)" ::: "memory");
            else          asm volatile("s_waitcnt vmcnt(0)" ::: "memory");
            __builtin_amdgcn_s_barrier();
            asm volatile("" ::: "memory");
        }
    };

    auto prologue = [&]() {
        STAGE(0, 0); STAGE(1, 1);       // pair 0
        STAGE(2, 2); STAGE(3, 3);       // pair 1
        asm volatile("s_waitcnt vmcnt(4)" ::: "memory");   // pair 0 landed
        __builtin_amdgcn_s_barrier();
        asm volatile("" ::: "memory");
    };

    // ---- pass 1 ----
    prologue();
    runPass();
    lsA += __shfl_xor(lsA, 32);
    lsB += __shfl_xor(lsB, 32);
    // ---- pass boundary: combine ks halves, compute state1 for both streams ----
    if (ks == 1) {
        #pragma unroll
        for (int i = 0; i < 8; ++i) {
            unsigned int u;
            asm("v_cvt_pk_bf16_f32 %0, %1, %2" : "=v"(u) : "v"(oA0[2*i]), "v"(oA0[2*i+1]));
            slotA[i*64 + l] = u;
            asm("v_cvt_pk_bf16_f32 %0, %1, %2" : "=v"(u) : "v"(oA1[2*i]), "v"(oA1[2*i+1]));
            slotA[(8+i)*64 + l] = u;
            asm("v_cvt_pk_bf16_f32 %0, %1, %2" : "=v"(u) : "v"(oB0[2*i]), "v"(oB0[2*i+1]));
            slotB[i*64 + l] = u;
            asm("v_cvt_pk_bf16_f32 %0, %1, %2" : "=v"(u) : "v"(oB1[2*i]), "v"(oB1[2*i+1]));
            slotB[(8+i)*64 + l] = u;
        }
        slsA[l] = lsA;
        slsB[l] = lsB;
        asm volatile("s_waitcnt lgkmcnt(0)" ::: "memory");
    }
    __builtin_amdgcn_s_barrier();
    asm volatile("" ::: "memory");
    if (ks == 0) {
        #pragma unroll
        for (int i = 0; i < 8; ++i) {
            unsigned int u = slotA[i*64 + l];
            oA0[2*i]   += __uint_as_float(u << 16);
            oA0[2*i+1] += __uint_as_float(u & 0xffff0000u);
            u = slotA[(8+i)*64 + l];
            oA1[2*i]   += __uint_as_float(u << 16);
            oA1[2*i+1] += __uint_as_float(u & 0xffff0000u);
            u = slotB[i*64 + l];
            oB0[2*i]   += __uint_as_float(u << 16);
            oB0[2*i+1] += __uint_as_float(u & 0xffff0000u);
            u = slotB[(8+i)*64 + l];
            oB1[2*i]   += __uint_as_float(u << 16);
            oB1[2*i+1] += __uint_as_float(u & 0xffff0000u);
        }
        float oscA = LOG2E / (lsA + slsA[l]);
        float oscB = LOG2E / (lsB + slsB[l]);
        unsigned int w0[8], w1[8], w2[8], w3[8];
        #pragma unroll
        for (int i = 0; i < 8; ++i) {
            float a0 = oA0[2*i]*oscA, a1 = oA0[2*i+1]*oscA;
            asm("v_cvt_pk_bf16_f32 %0, %1, %2" : "=v"(w0[i]) : "v"(a0), "v"(a1));
            float b0 = oA1[2*i]*oscA, b1 = oA1[2*i+1]*oscA;
            asm("v_cvt_pk_bf16_f32 %0, %1, %2" : "=v"(w1[i]) : "v"(b0), "v"(b1));
            float c0 = oB0[2*i]*oscB, c1 = oB0[2*i+1]*oscB;
            asm("v_cvt_pk_bf16_f32 %0, %1, %2" : "=v"(w2[i]) : "v"(c0), "v"(c1));
            float d0 = oB1[2*i]*oscB, d1 = oB1[2*i+1]*oscB;
            asm("v_cvt_pk_bf16_f32 %0, %1, %2" : "=v"(w3[i]) : "v"(d0), "v"(d1));
        }
        asm volatile("v_permlane32_swap_b32 %0, %1" : "+v"(w0[0]), "+v"(w0[2]));
        asm volatile("v_permlane32_swap_b32 %0, %1" : "+v"(w0[1]), "+v"(w0[3]));
        asm volatile("v_permlane32_swap_b32 %0, %1" : "+v"(w0[4]), "+v"(w0[6]));
        asm volatile("v_permlane32_swap_b32 %0, %1" : "+v"(w0[5]), "+v"(w0[7]));
        asm volatile("v_permlane32_swap_b32 %0, %1" : "+v"(w1[0]), "+v"(w1[2]));
        asm volatile("v_permlane32_swap_b32 %0, %1" : "+v"(w1[1]), "+v"(w1[3]));
        asm volatile("v_permlane32_swap_b32 %0, %1" : "+v"(w1[4]), "+v"(w1[6]));
        asm volatile("v_permlane32_swap_b32 %0, %1" : "+v"(w1[5]), "+v"(w1[7]));
        asm volatile("v_permlane32_swap_b32 %0, %1" : "+v"(w2[0]), "+v"(w2[2]));
        asm volatile("v_permlane32_swap_b32 %0, %1" : "+v"(w2[1]), "+v"(w2[3]));
        asm volatile("v_permlane32_swap_b32 %0, %1" : "+v"(w2[4]), "+v"(w2[6]));
        asm volatile("v_permlane32_swap_b32 %0, %1" : "+v"(w2[5]), "+v"(w2[7]));
        asm volatile("v_permlane32_swap_b32 %0, %1" : "+v"(w3[0]), "+v"(w3[2]));
        asm volatile("v_permlane32_swap_b32 %0, %1" : "+v"(w3[1]), "+v"(w3[3]));
        asm volatile("v_permlane32_swap_b32 %0, %1" : "+v"(w3[4]), "+v"(w3[6]));
        asm volatile("v_permlane32_swap_b32 %0, %1" : "+v"(w3[5]), "+v"(w3[7]));
        PW pa;
        pa.u[0]=w0[0]; pa.u[1]=w0[1]; pa.u[2]=w0[2]; pa.u[3]=w0[3]; qfA[0]=pa.s;
        pa.u[0]=w0[4]; pa.u[1]=w0[5]; pa.u[2]=w0[6]; pa.u[3]=w0[7]; qfA[1]=pa.s;
        pa.u[0]=w1[0]; pa.u[1]=w1[1]; pa.u[2]=w1[2]; pa.u[3]=w1[3]; qfA[2]=pa.s;
        pa.u[0]=w1[4]; pa.u[1]=w1[5]; pa.u[2]=w1[6]; pa.u[3]=w1[7]; qfA[3]=pa.s;
        pa.u[0]=w2[0]; pa.u[1]=w2[1]; pa.u[2]=w2[2]; pa.u[3]=w2[3]; qfB[0]=pa.s;
        pa.u[0]=w2[4]; pa.u[1]=w2[5]; pa.u[2]=w2[6]; pa.u[3]=w2[7]; qfB[1]=pa.s;
        pa.u[0]=w3[0]; pa.u[1]=w3[1]; pa.u[2]=w3[2]; pa.u[3]=w3[3]; qfB[2]=pa.s;
        pa.u[0]=w3[4]; pa.u[1]=w3[5]; pa.u[2]=w3[6]; pa.u[3]=w3[7]; qfB[3]=pa.s;
        #pragma unroll
        for (int i = 0; i < 8; ++i) {
            slotA[i*64 + l] = w0[i];
            slotA[(8+i)*64 + l] = w1[i];
            slotB[i*64 + l] = w2[i];
            slotB[(8+i)*64 + l] = w3[i];
        }
        asm volatile("s_waitcnt lgkmcnt(0)" ::: "memory");
    }
    __builtin_amdgcn_s_barrier();
    asm volatile("" ::: "memory");
    if (ks == 1) {
        PW pa;
        pa.u[0]=slotA[0*64+l]; pa.u[1]=slotA[1*64+l]; pa.u[2]=slotA[2*64+l]; pa.u[3]=slotA[3*64+l]; qfA[0]=pa.s;
        pa.u[0]=slotA[4*64+l]; pa.u[1]=slotA[5*64+l]; pa.u[2]=slotA[6*64+l]; pa.u[3]=slotA[7*64+l]; qfA[1]=pa.s;
        pa.u[0]=slotA[8*64+l]; pa.u[1]=slotA[9*64+l]; pa.u[2]=slotA[10*64+l]; pa.u[3]=slotA[11*64+l]; qfA[2]=pa.s;
        pa.u[0]=slotA[12*64+l]; pa.u[1]=slotA[13*64+l]; pa.u[2]=slotA[14*64+l]; pa.u[3]=slotA[15*64+l]; qfA[3]=pa.s;
        pa.u[0]=slotB[0*64+l]; pa.u[1]=slotB[1*64+l]; pa.u[2]=slotB[2*64+l]; pa.u[3]=slotB[3*64+l]; qfB[0]=pa.s;
        pa.u[0]=slotB[4*64+l]; pa.u[1]=slotB[5*64+l]; pa.u[2]=slotB[6*64+l]; pa.u[3]=slotB[7*64+l]; qfB[1]=pa.s;
        pa.u[0]=slotB[8*64+l]; pa.u[1]=slotB[9*64+l]; pa.u[2]=slotB[10*64+l]; pa.u[3]=slotB[11*64+l]; qfB[2]=pa.s;
        pa.u[0]=slotB[12*64+l]; pa.u[1]=slotB[13*64+l]; pa.u[2]=slotB[14*64+l]; pa.u[3]=slotB[15*64+l]; qfB[3]=pa.s;
    }
    asm volatile("s_waitcnt lgkmcnt(0)" ::: "memory");
    __builtin_amdgcn_s_barrier();
    asm volatile("" ::: "memory");
    oA0 = 0.0f; oA1 = 0.0f; oB0 = 0.0f; oB1 = 0.0f; lsA = 0.0f; lsB = 0.0f;
    // ---- pass 2 ----
    prologue();
    runPass();
    lsA += __shfl_xor(lsA, 32);
    lsB += __shfl_xor(lsB, 32);
    // ---- final combine + output ----
    if (ks == 1) {
        #pragma unroll
        for (int i = 0; i < 8; ++i) {
            unsigned int u;
            asm("v_cvt_pk_bf16_f32 %0, %1, %2" : "=v"(u) : "v"(oA0[2*i]), "v"(oA0[2*i+1]));
            slotA[i*64 + l] = u;
            asm("v_cvt_pk_bf16_f32 %0, %1, %2" : "=v"(u) : "v"(oA1[2*i]), "v"(oA1[2*i+1]));
            slotA[(8+i)*64 + l] = u;
            asm("v_cvt_pk_bf16_f32 %0, %1, %2" : "=v"(u) : "v"(oB0[2*i]), "v"(oB0[2*i+1]));
            slotB[i*64 + l] = u;
            asm("v_cvt_pk_bf16_f32 %0, %1, %2" : "=v"(u) : "v"(oB1[2*i]), "v"(oB1[2*i+1]));
            slotB[(8+i)*64 + l] = u;
        }
        slsA[l] = lsA;
        slsB[l] = lsB;
        asm volatile("s_waitcnt lgkmcnt(0)" ::: "memory");
    }
    __builtin_amdgcn_s_barrier();
    asm volatile("" ::: "memory");
    if (ks == 0) {
        #pragma unroll
        for (int i = 0; i < 8; ++i) {
            unsigned int u = slotA[i*64 + l];
            oA0[2*i]   += __uint_as_float(u << 16);
            oA0[2*i+1] += __uint_as_float(u & 0xffff0000u);
            u = slotA[(8+i)*64 + l];
            oA1[2*i]   += __uint_as_float(u << 16);
            oA1[2*i+1] += __uint_as_float(u & 0xffff0000u);
            u = slotB[i*64 + l];
            oB0[2*i]   += __uint_as_float(u << 16);
            oB0[2*i+1] += __uint_as_float(u & 0xffff0000u);
            u = slotB[(8+i)*64 + l];
            oB1[2*i]   += __uint_as_float(u << 16);
            oB1[2*i+1] += __uint_as_float(u & 0xffff0000u);
        }
        float oscA = 1.0f / (lsA + slsA[l]);
        float oscB = 1.0f / (lsB + slsB[l]);
        int bb = bh >> 4, hh = bh & 15;
        int rowA = q0 + wq*64 + q;
        unsigned short* orowA = outp + ((size_t)bb*SEQLEN + rowA)*HDIM + hh*HEADD;
        unsigned short* orowB = orowA + 32*HDIM;
        const int dtab[8] = {0,2,8,10,16,18,24,26};
        #pragma unroll
        for (int i = 0; i < 8; ++i) {
            int d = dtab[i] + 4*hi;
            unsigned int wv;
            float a0 = oA0[2*i]*oscA, a1 = oA0[2*i+1]*oscA;
            asm("v_cvt_pk_bf16_f32 %0, %1, %2" : "=v"(wv) : "v"(a0), "v"(a1));
            *(unsigned int*)(orowA + d) = wv;
            float b0 = oA1[2*i]*oscA, b1 = oA1[2*i+1]*oscA;
            asm("v_cvt_pk_bf16_f32 %0, %1, %2" : "=v"(wv) : "v"(b0), "v"(b1));
            *(unsigned int*)(orowA + 32 + d) = wv;
            float c0 = oB0[2*i]*oscB, c1 = oB0[2*i+1]*oscB;
            asm("v_cvt_pk_bf16_f32 %0, %1, %2" : "=v"(wv) : "v"(c0), "v"(c1));
            *(unsigned int*)(orowB + d) = wv;
            float d0 = oB1[2*i]*oscB, d1 = oB1[2*i+1]*oscB;
            asm("v_cvt_pk_bf16_f32 %0, %1, %2" : "=v"(wv) : "v"(d0), "v"(d1));
            *(unsigned int*)(orowB + 32 + d) = wv;
        }
    }
}

extern "C" void kernel_launch(void* const* d_in, const int* in_sizes, int n_in,
                              void* d_out, int out_size, void* d_ws, size_t ws_size,
                              hipStream_t stream) {
    const float* hs = (const float*)d_in[0];
    const float* Wq = (const float*)d_in[1];
    const float* bq = (const float*)d_in[2];
    const float* Wk = (const float*)d_in[3];
    const float* bk = (const float*)d_in[4];
    const float* Wv = (const float*)d_in[5];
    const float* bv = (const float*)d_in[6];
    const float* Wo = (const float*)d_in[7];
    const float* bo = (const float*)d_in[8];
    const float* lw = (const float*)d_in[9];
    const float* lb = (const float*)d_in[10];
    unsigned short* ws16 = (unsigned short*)d_ws;
    const size_t NE = (size_t)NROWS * HDIM;
    const size_t WE = (size_t)HDIM * HDIM;
    unsigned short* xn  = ws16;
    unsigned short* Wtq = xn + NE;       // Wtq/Wtk/Wtv/Wto contiguous
    unsigned short* Wto = Wtq + 3*WE;
    unsigned short* qb  = Wtq + 4*WE;
    unsigned short* kb  = qb + NE;
    unsigned short* vt  = kb + NE;
    unsigned short* s2  = vt + NE;

    prep_kernel<<<NROWS + 1024, 256, 0, stream>>>(hs, lw, lb, xn, Wq, Wk, Wv, Wo, Wtq);
    gemm_qkv_kernel<<<dim3(NROWS/128, 24), 256, 0, stream>>>(xn, Wtq, bq, bk, bv, qb, kb, vt);
    attn_fused_kernel<<<NBH*8, 512, 0, stream>>>(qb, kb, vt, s2);
    gemm_o_kernel<<<dim3(NROWS/128, HDIM/64), 256, 0, stream>>>(s2, Wto, bo, hs, (float*)d_out);
}